// Round 8
// baseline (313.288 us; speedup 1.0000x reference)
//
#include <hip/hip_runtime.h>
#include <math.h>

// Problem constants (from reference)
#define B  2
#define S  2048
#define DM 1024
#define H  16
#define Dh 64
#define BH (B*H)

typedef short  bf16x8 __attribute__((ext_vector_type(8)));
typedef float  f32x4  __attribute__((ext_vector_type(4)));

__device__ __forceinline__ unsigned short f2bf(float f) {
    unsigned u = __float_as_uint(f);
    u = (u + 0x7fffu + ((u >> 16) & 1u)) >> 16;   // RNE, no NaN inputs here
    return (unsigned short)u;
}

// gfx950 packed f32->bf16 (RNE) — one VALU op for two converts+pack.
__device__ __forceinline__ unsigned cvt_pk_bf16(float lo, float hi) {
    unsigned r;
    asm("v_cvt_pk_bf16_f32 %0, %1, %2" : "=v"(r) : "v"(lo), "v"(hi));
    return r;
}

// ---------------------------------------------------------------------------
// Kernel 0a: cast hidden_states + Wq|Wk|Wv (fp32) to bf16 workspace buffers.
// ---------------------------------------------------------------------------
__global__ __launch_bounds__(256) void cast_kernel(const float* __restrict__ X,
                                                   const float* __restrict__ Wq,
                                                   const float* __restrict__ Wk,
                                                   const float* __restrict__ Wv,
                                                   unsigned short* __restrict__ Xb,
                                                   unsigned short* __restrict__ Wb) {
    const long c = (long)(blockIdx.x * 256 + threadIdx.x) * 4;
    const float* src;
    unsigned short* dst;
    if (c < 4194304L) {
        src = X + c;  dst = Xb + c;
    } else {
        const long c2 = c - 4194304L;
        const int  wi = (int)(c2 >> 20);
        const long r  = c2 & 1048575L;
        src = (wi == 0 ? Wq : (wi == 1 ? Wk : Wv)) + r;
        dst = Wb + c2;
    }
    const float4 v = *(const float4*)src;
    ushort4 o;
    o.x = f2bf(v.x); o.y = f2bf(v.y); o.z = f2bf(v.z); o.w = f2bf(v.w);
    *(ushort4*)dst = o;
}

// ---------------------------------------------------------------------------
// Kernel 0b: RoPE cos/sin table: Tab[(b*S+s)*32 + i] = (cos, sin) of
//   pos[b,s] * 10000^(-i/32).  1 MB, L2-resident.
// ---------------------------------------------------------------------------
__global__ __launch_bounds__(256) void rope_tab_kernel(const int* __restrict__ pos,
                                                       float* __restrict__ Tab) {
    const int idx = blockIdx.x * 256 + threadIdx.x;   // < B*S*32 = 131072
    const int i  = idx & 31;
    const int bs = idx >> 5;
    const float p   = (float)pos[bs];
    const float inv = exp2f(-(float)i * 0.41524101186092029f);  // log2(1e4)/32
    float sn, cs;
    sincosf(p * inv, &sn, &cs);
    ((float2*)Tab)[idx] = make_float2(cs, sn);
}

// async global->LDS, 16B per lane
__device__ __forceinline__ void gload_lds16(const unsigned short* g, unsigned short* l) {
    __builtin_amdgcn_global_load_lds(
        (const __attribute__((address_space(1))) unsigned int*)g,
        (__attribute__((address_space(3))) unsigned int*)l,
        16, 0, 0);
}

// ---------------------------------------------------------------------------
// Kernel 1: fused QKV GEMM (R0 verified config: BK=32, 16 MFMA/barrier —
//   BK=64 regressed −19 µs in R3). global_load_lds staging with XOR chunk
//   swizzle. Epilogue: RoPE via table + LDS round-trip (Es, 2 halves) so ALL
//   global stores are coalesced 16B. V written transposed [B,H,Dh,S].
// ---------------------------------------------------------------------------
__global__ __launch_bounds__(256) void qkv_gemm(const unsigned short* __restrict__ Xb,
                                                const unsigned short* __restrict__ Wb,
                                                const float* __restrict__ Tab,
                                                unsigned short* __restrict__ Qb,
                                                unsigned short* __restrict__ Kb,
                                                unsigned short* __restrict__ Vb) {
    __shared__ __align__(16) unsigned short As[128 * 32];
    __shared__ __align__(16) unsigned short Bs[128 * 32];
    __shared__ __align__(16) unsigned short Es[64 * 136];   // epilogue staging

    const int tid  = threadIdx.x;
    const int w    = tid >> 6;
    const int lane = tid & 63;
    const int col  = lane & 15;
    const int quad = lane >> 4;
    const int m0 = blockIdx.x * 128;
    const int n0 = blockIdx.y * 128;
    const int mw = (w & 1) * 64;
    const int nw = (w >> 1) * 64;

    // staging: lane i loads row i>>2, global chunk (i&3)^(row&3)  (XOR swizzle)
    const int srow = lane >> 2;
    const int sk8  = (((lane & 3) ^ (srow & 3))) * 8;

    f32x4 acc[4][4] = {};

    for (int k0 = 0; k0 < 1024; k0 += 32) {
        __syncthreads();
        #pragma unroll
        for (int it = 0; it < 2; ++it) {
            const int rbase = w * 16 + it * 64;
            gload_lds16(Xb + (size_t)(m0 + rbase + srow) * 1024 + k0 + sk8,
                        &As[rbase * 32]);
            gload_lds16(Wb + (size_t)(n0 + rbase + srow) * 1024 + k0 + sk8,
                        &Bs[rbase * 32]);
        }
        __syncthreads();

        // global k-chunk quad lives at LDS slot quad^(row&3); row&3 == col&3
        const int fs = (quad ^ (col & 3)) * 8;
        bf16x8 a[4], bb[4];
        #pragma unroll
        for (int i = 0; i < 4; ++i)
            a[i] = *(const bf16x8*)&As[(mw + i * 16 + col) * 32 + fs];
        #pragma unroll
        for (int j = 0; j < 4; ++j)
            bb[j] = *(const bf16x8*)&Bs[(nw + j * 16 + col) * 32 + fs];
        #pragma unroll
        for (int i = 0; i < 4; ++i)
            #pragma unroll
            for (int j = 0; j < 4; ++j)
                acc[i][j] = __builtin_amdgcn_mfma_f32_16x16x32_bf16(a[i], bb[j], acc[i][j], 0, 0, 0);
    }

    // ---- epilogue ----
    const int wsel = n0 >> 10;                 // 0=Q, 1=K, 2=V
    const int hh0  = (n0 & 1023) >> 6;         // base head of this n-tile
    const int bb2  = m0 >> 11;                 // batch (block never straddles)
    const int ssb  = m0 & 2047;                // seq base

    if (wsel == 2) {
        // V -> [B,H,Dh,S]; Es[dl][ssl] per dcol-half, b64 packed writes
        #pragma unroll
        for (int half = 0; half < 2; ++half) {
            __syncthreads();
            if ((w >> 1) == half) {            // waves whose nw == half*64
                #pragma unroll
                for (int i = 0; i < 4; ++i) {
                    const int sl = mw + i * 16 + quad * 4;
                    #pragma unroll
                    for (int j = 0; j < 4; ++j) {
                        const int dl = j * 16 + col;     // 0..63 within half
                        ushort4 ov;
                        ov.x = f2bf(acc[i][j][0]); ov.y = f2bf(acc[i][j][1]);
                        ov.z = f2bf(acc[i][j][2]); ov.w = f2bf(acc[i][j][3]);
                        *(ushort4*)&Es[dl * 136 + sl] = ov;
                    }
                }
            }
            __syncthreads();
            #pragma unroll
            for (int k = 0; k < 4; ++k) {
                const int c  = tid + k * 256;
                const int dl = c >> 4;               // 0..63 within half
                const int s8 = (c & 15) * 8;
                const int d  = half * 64 + dl;
                const bf16x8 v = *(const bf16x8*)&Es[dl * 136 + s8];
                *(bf16x8*)(Vb + ((size_t)(bb2 * H + hh0 + (d >> 6)) * Dh + (d & 63)) * S
                           + ssb + s8) = v;
            }
        }
    } else {
        // Q/K with fused RoPE from table; Es[row][d] per m-half
        unsigned short* dp = (wsel == 0) ? Qb : Kb;
        const float qscale = (wsel == 0) ? 0.125f : 1.0f;   // D^-0.5 for Q
        #pragma unroll
        for (int half = 0; half < 2; ++half) {
            __syncthreads();
            if ((w & 1) == half) {             // waves whose mw == half*64
                #pragma unroll
                for (int i = 0; i < 4; ++i) {
                    #pragma unroll
                    for (int r = 0; r < 4; ++r) {
                        const int rl = i * 16 + quad * 4 + r;   // 0..63 local
                        const int ss = ssb + half * 64 + rl;
                        const float2 t0 = ((const float2*)Tab)[(size_t)(bb2 * S + ss) * 32 + col];
                        const float2 t1 = ((const float2*)Tab)[(size_t)(bb2 * S + ss) * 32 + col + 16];
                        const float a0 = acc[i][0][r] * qscale, a1 = acc[i][1][r] * qscale;
                        const float a2 = acc[i][2][r] * qscale, a3 = acc[i][3][r] * qscale;
                        unsigned short* e = &Es[rl * 136 + nw];
                        e[col]      = f2bf(a0 * t0.x - a2 * t0.y);
                        e[col + 16] = f2bf(a1 * t1.x - a3 * t1.y);
                        e[col + 32] = f2bf(a2 * t0.x + a0 * t0.y);
                        e[col + 48] = f2bf(a3 * t1.x + a1 * t1.y);
                    }
                }
            }
            __syncthreads();
            #pragma unroll
            for (int k = 0; k < 4; ++k) {
                const int c  = tid + k * 256;
                const int rl = c >> 4;               // 0..63 local row
                const int d8 = (c & 15) * 8;
                const bf16x8 v = *(const bf16x8*)&Es[rl * 136 + d8];
                *(bf16x8*)(dp + ((size_t)(bb2 * H + hh0 + (d8 >> 6)) * S
                                 + ssb + half * 64 + rl) * Dh + (d8 & 63)) = v;
            }
        }
    }
}

// ---------------------------------------------------------------------------
// Kernel 2: flash attention — DE-STAGED K/V (R8). K/V per (b,h) is 512 KB,
//   L2-resident, shared by 16 blocks: LDS staging of it was pure overhead
//   (Common-mistake #7; LDS pipe was the busiest resource at ~55%+conflicts,
//   and staging forced the per-tile barrier lockstep that R5/R7 nulls showed
//   can't be scheduled around). Now: K and V fragments load straight from
//   global (L2-hot) into registers, software-pipelined one tile ahead
//   (K prefetched after QK consumes it; V after PV; mask after mask-add —
//   every issue->use window >= ~450 cyc > L2 latency). LDS holds ONLY the
//   wave-private P̃ transpose buffer. ZERO barriers — waves self-paced.
//   Values byte-identical to the staged path -> absmax unchanged.
//   VGPR grows (~200, kf+vf=64 regs): launch_bounds(256,2) caps at 256;
//   grid provides only 2 waves/SIMD anyway, so no occupancy loss possible.
//   grid = (S/128, B*H) = 512 blocks, 256 thr.
// ---------------------------------------------------------------------------
#define KSd 72
#define LOG2E  1.4426950408889634f
#define NEG8L (-11.541560327111707f)      // -8 * log2(e); exp(s-8) == exp2(fma)
#define NT (S / 64)

__global__ __launch_bounds__(256, 2) void attn_kernel(const unsigned short* __restrict__ Q,
                                                      const unsigned short* __restrict__ K,
                                                      const unsigned short* __restrict__ V,
                                                      const float* __restrict__ mask,
                                                      float* __restrict__ out) {
    __shared__ __align__(16) unsigned short Ps[4 * 32 * KSd];   // P̃ only (18.4 KB)

    const int tid  = threadIdx.x;
    const int w    = tid >> 6;
    const int lane = tid & 63;
    const int col  = lane & 15;
    const int quad = lane >> 4;
    const int bh   = blockIdx.y;
    const int b    = bh >> 4, h = bh & 15;
    const int q0   = blockIdx.x * 128;
    const int qw   = q0 + w * 32;             // wave's q base (32 rows)

    // Q fragments: qa[u][kc] — lane holds Q[q=qw+u*16+col][kc*32+quad*8 ..+7]
    bf16x8 qa[2][2];
    #pragma unroll
    for (int u = 0; u < 2; ++u) {
        const unsigned short* qrow = Q + ((size_t)bh * S + qw + u * 16 + col) * Dh;
        qa[u][0] = *(const bf16x8*)(qrow + quad * 8);
        qa[u][1] = *(const bf16x8*)(qrow + 32 + quad * 8);
    }

    f32x4 o[4][2] = {};                        // O^T frags: [d-frag g][q-frag u]
    float lsum[2] = {0.f, 0.f};
    const float* mbase = mask + (size_t)b * S * S;
    unsigned short* pw = Ps + w * 32 * KSd;

    // per-lane base pointers for direct K/V fragment loads:
    // K frag (f,kc): K[key = kt*64 + f*16+col][d = kc*32 + quad*8 .. +7]
    // V frag (g,kc): V[d = g*16+col][key = kt*64 + kc*32 + quad*8 .. +7]
    const unsigned short* Kl = K + (size_t)bh * S * Dh + (size_t)col * Dh + quad * 8;
    const unsigned short* Vl = V + (size_t)bh * Dh * S + (size_t)col * S + quad * 8;

    bf16x8 kf[4][2], vf[4][2];
    float4 mv[4][2];

    // ---- prologue: tile-0 K, V, mask into registers ----
    #pragma unroll
    for (int f = 0; f < 4; ++f)
        #pragma unroll
        for (int kc = 0; kc < 2; ++kc)
            kf[f][kc] = *(const bf16x8*)(Kl + (size_t)(f * 16) * Dh + kc * 32);
    #pragma unroll
    for (int g = 0; g < 4; ++g)
        #pragma unroll
        for (int kc = 0; kc < 2; ++kc)
            vf[g][kc] = *(const bf16x8*)(Vl + (size_t)(g * 16) * S + kc * 32);
    #pragma unroll
    for (int u = 0; u < 2; ++u)
        #pragma unroll
        for (int f = 0; f < 4; ++f)
            mv[f][u] = *(const float4*)(mbase + (size_t)(qw + u * 16 + col) * S
                                        + f * 16 + quad * 4);

    for (int kt = 0; kt < NT; ++kt) {
        // ---- S^T = K · Q^T : C[m=key][n=q] (kf consumed here) ----
        f32x4 sc[4][2] = {};
        #pragma unroll
        for (int f = 0; f < 4; ++f)
            #pragma unroll
            for (int u = 0; u < 2; ++u) {
                sc[f][u] = __builtin_amdgcn_mfma_f32_16x16x32_bf16(kf[f][0], qa[u][0], sc[f][u], 0, 0, 0);
                sc[f][u] = __builtin_amdgcn_mfma_f32_16x16x32_bf16(kf[f][1], qa[u][1], sc[f][u], 0, 0, 0);
            }

        // ---- kf dead: issue K(kt+1) loads (window: softmax+PV ~700cyc) ----
        if (kt + 1 < NT) {
            const unsigned short* kp = Kl + (size_t)(kt + 1) * 64 * Dh;
            #pragma unroll
            for (int f = 0; f < 4; ++f)
                #pragma unroll
                for (int kc = 0; kc < 2; ++kc)
                    kf[f][kc] = *(const bf16x8*)(kp + (size_t)(f * 16) * Dh + kc * 32);
        }

        // ---- mask add (consumes mv) ----
        #pragma unroll
        for (int u = 0; u < 2; ++u)
            #pragma unroll
            for (int f = 0; f < 4; ++f) {
                sc[f][u][0] += mv[f][u].x; sc[f][u][1] += mv[f][u].y;
                sc[f][u][2] += mv[f][u].z; sc[f][u][3] += mv[f][u].w;
            }

        // ---- mv dead: issue mask(kt+1) loads ----
        if (kt + 1 < NT) {
            #pragma unroll
            for (int u = 0; u < 2; ++u)
                #pragma unroll
                for (int f = 0; f < 4; ++f)
                    mv[f][u] = *(const float4*)(mbase + (size_t)(qw + u * 16 + col) * S
                                                + (kt + 1) * 64 + f * 16 + quad * 4);
        }

        // ---- static-shift softmax numerator + packed P̃ store ----
        #pragma unroll
        for (int u = 0; u < 2; ++u) {
            #pragma unroll
            for (int f = 0; f < 4; ++f)
                #pragma unroll
                for (int r = 0; r < 4; ++r) {
                    const float pv = __builtin_amdgcn_exp2f(
                        __builtin_fmaf(sc[f][u][r], LOG2E, NEG8L));
                    sc[f][u][r] = pv;
                    lsum[u] += pv;
                }
            unsigned short* pq = pw + (u * 16 + col) * KSd;
            #pragma unroll
            for (int f = 0; f < 4; ++f) {
                *(uint2*)&pq[f * 16 + quad * 4] =
                    make_uint2(cvt_pk_bf16(sc[f][u][0], sc[f][u][1]),
                               cvt_pk_bf16(sc[f][u][2], sc[f][u][3]));
            }
        }

        // wave-private Ps write->read ordering (same-wave): LDS wait + fence.
        asm volatile("s_waitcnt lgkmcnt(0)" ::: "memory");
        __builtin_amdgcn_sched_barrier(0);

        // ---- O^T += V^T · P̃ (vf consumed here) ----
        #pragma unroll
        for (int kc = 0; kc < 2; ++kc) {
            bf16x8 pb[2];
            #pragma unroll
            for (int u = 0; u < 2; ++u)
                pb[u] = *(const bf16x8*)&pw[(u * 16 + col) * KSd + kc * 32 + quad * 8];
            #pragma unroll
            for (int g = 0; g < 4; ++g)
                #pragma unroll
                for (int u = 0; u < 2; ++u)
                    o[g][u] = __builtin_amdgcn_mfma_f32_16x16x32_bf16(vf[g][kc], pb[u], o[g][u], 0, 0, 0);
        }

        // ---- vf dead: issue V(kt+1) loads (window: next QK+softmax) ----
        if (kt + 1 < NT) {
            const unsigned short* vp = Vl + (size_t)(kt + 1) * 64;
            #pragma unroll
            for (int g = 0; g < 4; ++g)
                #pragma unroll
                for (int kc = 0; kc < 2; ++kc)
                    vf[g][kc] = *(const bf16x8*)(vp + (size_t)(g * 16) * S + kc * 32);
        }
        // NO barrier: waves are fully independent (Ps is wave-private).
    }

    // ---- deferred l reduction (quads hold disjoint key subsets) ----
    #pragma unroll
    for (int u = 0; u < 2; ++u) {
        lsum[u] += __shfl_xor(lsum[u], 16, 64);
        lsum[u] += __shfl_xor(lsum[u], 32, 64);
    }

    // ---- epilogue: lane (quad,r,col) holds O[q=qw+u*16+col][d=g*16+quad*4+r]
    #pragma unroll
    for (int u = 0; u < 2; ++u) {
        const float inv = 1.f / lsum[u];
        float* op = out + ((size_t)b * S + qw + u * 16 + col) * DM + h * Dh + quad * 4;
        #pragma unroll
        for (int g = 0; g < 4; ++g) {
            float4 ov;
            ov.x = o[g][u][0] * inv; ov.y = o[g][u][1] * inv;
            ov.z = o[g][u][2] * inv; ov.w = o[g][u][3] * inv;
            *(float4*)(op + g * 16) = ov;
        }
    }
}

// ---------------------------------------------------------------------------
extern "C" void kernel_launch(void* const* d_in, const int* in_sizes, int n_in,
                              void* d_out, int out_size, void* d_ws, size_t ws_size,
                              hipStream_t stream) {
    const float* hs   = (const float*)d_in[0];  // (B,S,DM)
    const float* mask = (const float*)d_in[1];  // (B,1,S,S)
    const int*   pos  = (const int*)  d_in[2];  // (B,S)
    const float* Wq   = (const float*)d_in[3];
    const float* Wk   = (const float*)d_in[4];
    const float* Wv   = (const float*)d_in[5];
    float* out = (float*)d_out;

    // workspace (ushort units): Xb 4,194,304 | Wb 3,145,728 |
    //   Qb,Kb [B,H,S,Dh], Vb [B,H,Dh,S] each 4,194,304 | Tab 1 MB (float2)
    unsigned short* Xb = (unsigned short*)d_ws;
    unsigned short* Wb = Xb + 4194304;
    unsigned short* Qb = Wb + 3145728;
    unsigned short* Kb = Qb + 4194304;
    unsigned short* Vb = Kb + 4194304;
    float*          Tab = (float*)(Vb + 4194304);   // 262144 floats

    cast_kernel<<<7168, 256, 0, stream>>>(hs, Wq, Wk, Wv, Xb, Wb);
    rope_tab_kernel<<<512, 256, 0, stream>>>(pos, Tab);
    qkv_gemm<<<dim3(32, 24), 256, 0, stream>>>(Xb, Wb, Tab, Qb, Kb, Vb);
    attn_kernel<<<dim3(S / 128, BH), 256, 0, stream>>>(Qb, Kb, Vb, mask, out);
}

// Round 9
// 231.422 us; speedup vs baseline: 1.3537x; 1.3537x over previous
//
#include <hip/hip_runtime.h>
#include <math.h>

// Problem constants (from reference)
#define B  2
#define S  2048
#define DM 1024
#define H  16
#define Dh 64
#define BH (B*H)

typedef short  bf16x8 __attribute__((ext_vector_type(8)));
typedef float  f32x4  __attribute__((ext_vector_type(4)));

__device__ __forceinline__ unsigned short f2bf(float f) {
    unsigned u = __float_as_uint(f);
    u = (u + 0x7fffu + ((u >> 16) & 1u)) >> 16;   // RNE, no NaN inputs here
    return (unsigned short)u;
}

// gfx950 packed f32->bf16 (RNE) — one VALU op for two converts+pack.
__device__ __forceinline__ unsigned cvt_pk_bf16(float lo, float hi) {
    unsigned r;
    asm("v_cvt_pk_bf16_f32 %0, %1, %2" : "=v"(r) : "v"(lo), "v"(hi));
    return r;
}

// Barrier that waits ONLY on LDS ops (lgkmcnt), leaving global-load register
// prefetch in flight across the barrier. Two-sided compiler fence is REQUIRED
// (R6 failure: s_barrier is IntrNoMem; without the trailing fence, post-
// barrier LDS reads hoist between the waitcnt and the barrier).
__device__ __forceinline__ void lds_barrier() {
    asm volatile("s_waitcnt lgkmcnt(0)" ::: "memory");
    __builtin_amdgcn_s_barrier();
    asm volatile("" ::: "memory");
}

// ---------------------------------------------------------------------------
// Kernel 0a: cast hidden_states + Wq|Wk|Wv (fp32) to bf16 workspace buffers.
// ---------------------------------------------------------------------------
__global__ __launch_bounds__(256) void cast_kernel(const float* __restrict__ X,
                                                   const float* __restrict__ Wq,
                                                   const float* __restrict__ Wk,
                                                   const float* __restrict__ Wv,
                                                   unsigned short* __restrict__ Xb,
                                                   unsigned short* __restrict__ Wb) {
    const long c = (long)(blockIdx.x * 256 + threadIdx.x) * 4;
    const float* src;
    unsigned short* dst;
    if (c < 4194304L) {
        src = X + c;  dst = Xb + c;
    } else {
        const long c2 = c - 4194304L;
        const int  wi = (int)(c2 >> 20);
        const long r  = c2 & 1048575L;
        src = (wi == 0 ? Wq : (wi == 1 ? Wk : Wv)) + r;
        dst = Wb + c2;
    }
    const float4 v = *(const float4*)src;
    ushort4 o;
    o.x = f2bf(v.x); o.y = f2bf(v.y); o.z = f2bf(v.z); o.w = f2bf(v.w);
    *(ushort4*)dst = o;
}

// ---------------------------------------------------------------------------
// Kernel 0b: RoPE cos/sin table: Tab[(b*S+s)*32 + i] = (cos, sin) of
//   pos[b,s] * 10000^(-i/32).  1 MB, L2-resident.
// ---------------------------------------------------------------------------
__global__ __launch_bounds__(256) void rope_tab_kernel(const int* __restrict__ pos,
                                                       float* __restrict__ Tab) {
    const int idx = blockIdx.x * 256 + threadIdx.x;   // < B*S*32 = 131072
    const int i  = idx & 31;
    const int bs = idx >> 5;
    const float p   = (float)pos[bs];
    const float inv = exp2f(-(float)i * 0.41524101186092029f);  // log2(1e4)/32
    float sn, cs;
    sincosf(p * inv, &sn, &cs);
    ((float2*)Tab)[idx] = make_float2(cs, sn);
}

// async global->LDS, 16B per lane
__device__ __forceinline__ void gload_lds16(const unsigned short* g, unsigned short* l) {
    __builtin_amdgcn_global_load_lds(
        (const __attribute__((address_space(1))) unsigned int*)g,
        (__attribute__((address_space(3))) unsigned int*)l,
        16, 0, 0);
}

// ---------------------------------------------------------------------------
// Kernel 1: fused QKV GEMM (R0 verified config: BK=32, 16 MFMA/barrier).
//   NEW this round: XCD-aware block swizzle (T1). orig dispatch index is
//   round-robined across the 8 XCDs; remap wg=(orig&7)*96+orig>>3 so each
//   XCD owns a CONTIGUOUS chunk of 96 logical tiles = 4 consecutive m-panels
//   (A-chunk 4x128 rows = 1 MB -> per-XCD L2-resident) across all 24
//   n-panels. Bijective since 768 % 8 == 0.
// ---------------------------------------------------------------------------
__global__ __launch_bounds__(256) void qkv_gemm(const unsigned short* __restrict__ Xb,
                                                const unsigned short* __restrict__ Wb,
                                                const float* __restrict__ Tab,
                                                unsigned short* __restrict__ Qb,
                                                unsigned short* __restrict__ Kb,
                                                unsigned short* __restrict__ Vb) {
    __shared__ __align__(16) unsigned short As[128 * 32];
    __shared__ __align__(16) unsigned short Bs[128 * 32];
    __shared__ __align__(16) unsigned short Es[64 * 136];   // epilogue staging

    const int tid  = threadIdx.x;
    const int w    = tid >> 6;
    const int lane = tid & 63;
    const int col  = lane & 15;
    const int quad = lane >> 4;
    // XCD swizzle: orig -> wg (bijective, 768 = 8 XCDs x 96)
    const int orig = blockIdx.y * 32 + blockIdx.x;
    const int wg   = (orig & 7) * 96 + (orig >> 3);
    const int m0 = (wg / 24) * 128;
    const int n0 = (wg % 24) * 128;
    const int mw = (w & 1) * 64;
    const int nw = (w >> 1) * 64;

    // staging: lane i loads row i>>2, global chunk (i&3)^(row&3)  (XOR swizzle)
    const int srow = lane >> 2;
    const int sk8  = (((lane & 3) ^ (srow & 3))) * 8;

    f32x4 acc[4][4] = {};

    for (int k0 = 0; k0 < 1024; k0 += 32) {
        __syncthreads();
        #pragma unroll
        for (int it = 0; it < 2; ++it) {
            const int rbase = w * 16 + it * 64;
            gload_lds16(Xb + (size_t)(m0 + rbase + srow) * 1024 + k0 + sk8,
                        &As[rbase * 32]);
            gload_lds16(Wb + (size_t)(n0 + rbase + srow) * 1024 + k0 + sk8,
                        &Bs[rbase * 32]);
        }
        __syncthreads();

        // global k-chunk quad lives at LDS slot quad^(row&3); row&3 == col&3
        const int fs = (quad ^ (col & 3)) * 8;
        bf16x8 a[4], bb[4];
        #pragma unroll
        for (int i = 0; i < 4; ++i)
            a[i] = *(const bf16x8*)&As[(mw + i * 16 + col) * 32 + fs];
        #pragma unroll
        for (int j = 0; j < 4; ++j)
            bb[j] = *(const bf16x8*)&Bs[(nw + j * 16 + col) * 32 + fs];
        #pragma unroll
        for (int i = 0; i < 4; ++i)
            #pragma unroll
            for (int j = 0; j < 4; ++j)
                acc[i][j] = __builtin_amdgcn_mfma_f32_16x16x32_bf16(a[i], bb[j], acc[i][j], 0, 0, 0);
    }

    // ---- epilogue ----
    const int wsel = n0 >> 10;                 // 0=Q, 1=K, 2=V
    const int hh0  = (n0 & 1023) >> 6;         // base head of this n-tile
    const int bb2  = m0 >> 11;                 // batch (block never straddles)
    const int ssb  = m0 & 2047;                // seq base

    if (wsel == 2) {
        // V -> [B,H,Dh,S]; Es[dl][ssl] per dcol-half, b64 packed writes
        #pragma unroll
        for (int half = 0; half < 2; ++half) {
            __syncthreads();
            if ((w >> 1) == half) {            // waves whose nw == half*64
                #pragma unroll
                for (int i = 0; i < 4; ++i) {
                    const int sl = mw + i * 16 + quad * 4;
                    #pragma unroll
                    for (int j = 0; j < 4; ++j) {
                        const int dl = j * 16 + col;     // 0..63 within half
                        ushort4 ov;
                        ov.x = f2bf(acc[i][j][0]); ov.y = f2bf(acc[i][j][1]);
                        ov.z = f2bf(acc[i][j][2]); ov.w = f2bf(acc[i][j][3]);
                        *(ushort4*)&Es[dl * 136 + sl] = ov;
                    }
                }
            }
            __syncthreads();
            #pragma unroll
            for (int k = 0; k < 4; ++k) {
                const int c  = tid + k * 256;
                const int dl = c >> 4;               // 0..63 within half
                const int s8 = (c & 15) * 8;
                const int d  = half * 64 + dl;
                const bf16x8 v = *(const bf16x8*)&Es[dl * 136 + s8];
                *(bf16x8*)(Vb + ((size_t)(bb2 * H + hh0 + (d >> 6)) * Dh + (d & 63)) * S
                           + ssb + s8) = v;
            }
        }
    } else {
        // Q/K with fused RoPE from table; Es[row][d] per m-half
        unsigned short* dp = (wsel == 0) ? Qb : Kb;
        const float qscale = (wsel == 0) ? 0.125f : 1.0f;   // D^-0.5 for Q
        #pragma unroll
        for (int half = 0; half < 2; ++half) {
            __syncthreads();
            if ((w & 1) == half) {             // waves whose mw == half*64
                #pragma unroll
                for (int i = 0; i < 4; ++i) {
                    #pragma unroll
                    for (int r = 0; r < 4; ++r) {
                        const int rl = i * 16 + quad * 4 + r;   // 0..63 local
                        const int ss = ssb + half * 64 + rl;
                        const float2 t0 = ((const float2*)Tab)[(size_t)(bb2 * S + ss) * 32 + col];
                        const float2 t1 = ((const float2*)Tab)[(size_t)(bb2 * S + ss) * 32 + col + 16];
                        const float a0 = acc[i][0][r] * qscale, a1 = acc[i][1][r] * qscale;
                        const float a2 = acc[i][2][r] * qscale, a3 = acc[i][3][r] * qscale;
                        unsigned short* e = &Es[rl * 136 + nw];
                        e[col]      = f2bf(a0 * t0.x - a2 * t0.y);
                        e[col + 16] = f2bf(a1 * t1.x - a3 * t1.y);
                        e[col + 32] = f2bf(a2 * t0.x + a0 * t0.y);
                        e[col + 48] = f2bf(a3 * t1.x + a1 * t1.y);
                    }
                }
            }
            __syncthreads();
            #pragma unroll
            for (int k = 0; k < 4; ++k) {
                const int c  = tid + k * 256;
                const int rl = c >> 4;               // 0..63 local row
                const int d8 = (c & 15) * 8;
                const bf16x8 v = *(const bf16x8*)&Es[rl * 136 + d8];
                *(bf16x8*)(dp + ((size_t)(bb2 * H + hh0 + (d8 >> 6)) * S
                                 + ssb + half * 64 + rl) * Dh + (d8 & 63)) = v;
            }
        }
    }
}

// ---------------------------------------------------------------------------
// Kernel 2: flash attention — R7 verified pipeline (counted-wait barriers,
//   mask/K/V register prefetch, LDS K/V staging for coalescing — R8 proved
//   de-staging loses 2x to uncoalesced fragment loads). NEW this round:
//   8 waves x 256-q-tile. grid = (S/256, BH) = 256 blocks = EXACTLY 1/CU
//   (old 512-block grid showed 18.5% occupancy < 25% => dispatch imbalance).
//   K/V staging per wave HALVES (8 waves share the 64-key tile: 1 gload +
//   1 LDS write per wave per tile, was 2+2). Per-wave register state
//   unchanged. LDS 73.7 KB (1 block/CU by grid anyway).
// ---------------------------------------------------------------------------
#define KSd 72
#define LOG2E  1.4426950408889634f
#define NEG8L (-11.541560327111707f)      // -8 * log2(e); exp(s-8) == exp2(fma)
#define NT (S / 64)

__global__ __launch_bounds__(512) void attn_kernel(const unsigned short* __restrict__ Q,
                                                   const unsigned short* __restrict__ K,
                                                   const unsigned short* __restrict__ V,
                                                   const float* __restrict__ mask,
                                                   float* __restrict__ out) {
    __shared__ __align__(16) unsigned short Ks[2][64 * KSd];   // [key][d]
    __shared__ __align__(16) unsigned short Vt[2][64 * KSd];   // [d][key]
    __shared__ __align__(16) unsigned short Ps[8 * 32 * KSd];

    const int tid  = threadIdx.x;
    const int w    = tid >> 6;                // 0..7
    const int lane = tid & 63;
    const int col  = lane & 15;
    const int quad = lane >> 4;
    const int bh   = blockIdx.y;
    const int b    = bh >> 4, h = bh & 15;
    const int q0   = blockIdx.x * 256;
    const int qw   = q0 + w * 32;             // wave's q base (32 rows)

    // staging: 512 threads cover the 64x64 bf16 tile in ONE chunk each
    const int srow = tid >> 3;            // 0..63
    const int sc8  = (tid & 7) * 8;

    // Q fragments: qa[u][kc] — lane holds Q[q=qw+u*16+col][kc*32+quad*8 ..+7]
    bf16x8 qa[2][2];
    #pragma unroll
    for (int u = 0; u < 2; ++u) {
        const unsigned short* qrow = Q + ((size_t)bh * S + qw + u * 16 + col) * Dh;
        qa[u][0] = *(const bf16x8*)(qrow + quad * 8);
        qa[u][1] = *(const bf16x8*)(qrow + 32 + quad * 8);
    }

    f32x4 o[4][2] = {};                        // O^T frags: [d-frag g][q-frag u]
    float lsum[2] = {0.f, 0.f};
    const float* mbase = mask + (size_t)b * S * S;
    unsigned short* pw = Ps + w * 32 * KSd;
    const unsigned short* Kbase = K + (size_t)bh * S * Dh;
    const unsigned short* Vbase = V + (size_t)bh * Dh * S;   // transposed

    // ---- prologue: tile0 K/V + mask(tile0) into regs; stage tile0 to LDS
    //      buffer 0; then pre-issue tile1 K/V loads (drained at kt=0). ----
    bf16x8 kp, vp;
    float4 mv[4][2];
    kp = *(const bf16x8*)(Kbase + (size_t)srow * Dh + sc8);
    vp = *(const bf16x8*)(Vbase + (size_t)srow * S + sc8);
    #pragma unroll
    for (int u = 0; u < 2; ++u)
        #pragma unroll
        for (int f = 0; f < 4; ++f)
            mv[f][u] = *(const float4*)(mbase + (size_t)(qw + u * 16 + col) * S
                                        + f * 16 + quad * 4);
    *(bf16x8*)&Ks[0][srow * KSd + sc8] = kp;
    *(bf16x8*)&Vt[0][srow * KSd + sc8] = vp;
    // issue tile1 (stays in flight across the barrier)
    kp = *(const bf16x8*)(Kbase + (size_t)(64 + srow) * Dh + sc8);
    vp = *(const bf16x8*)(Vbase + (size_t)srow * S + 64 + sc8);
    lds_barrier();

    for (int kt = 0; kt < NT; ++kt) {
        const int cur = kt & 1;

        // ---- S^T = K · Q^T : C[m=key][n=q] ----
        f32x4 sc[4][2] = {};
        #pragma unroll
        for (int f = 0; f < 4; ++f) {
            const bf16x8 ka0 = *(const bf16x8*)&Ks[cur][(f * 16 + col) * KSd + quad * 8];
            const bf16x8 ka1 = *(const bf16x8*)&Ks[cur][(f * 16 + col) * KSd + 32 + quad * 8];
            #pragma unroll
            for (int u = 0; u < 2; ++u) {
                sc[f][u] = __builtin_amdgcn_mfma_f32_16x16x32_bf16(ka0, qa[u][0], sc[f][u], 0, 0, 0);
                sc[f][u] = __builtin_amdgcn_mfma_f32_16x16x32_bf16(ka1, qa[u][1], sc[f][u], 0, 0, 0);
            }
        }

        // ---- static-shift softmax numerator + packed P̃ store (consumes mv) ----
        #pragma unroll
        for (int u = 0; u < 2; ++u) {
            #pragma unroll
            for (int f = 0; f < 4; ++f) {
                sc[f][u][0] += mv[f][u].x; sc[f][u][1] += mv[f][u].y;
                sc[f][u][2] += mv[f][u].z; sc[f][u][3] += mv[f][u].w;
            }
            #pragma unroll
            for (int f = 0; f < 4; ++f)
                #pragma unroll
                for (int r = 0; r < 4; ++r) {
                    const float pv = __builtin_amdgcn_exp2f(
                        __builtin_fmaf(sc[f][u][r], LOG2E, NEG8L));
                    sc[f][u][r] = pv;
                    lsum[u] += pv;
                }
            unsigned short* pq = pw + (u * 16 + col) * KSd;
            #pragma unroll
            for (int f = 0; f < 4; ++f) {
                *(uint2*)&pq[f * 16 + quad * 4] =
                    make_uint2(cvt_pk_bf16(sc[f][u][0], sc[f][u][1]),
                               cvt_pk_bf16(sc[f][u][2], sc[f][u][3]));
            }
        }

        // ---- mv dead: issue mask loads for tile kt+1 directly into mv ----
        if (kt + 1 < NT) {
            #pragma unroll
            for (int u = 0; u < 2; ++u)
                #pragma unroll
                for (int f = 0; f < 4; ++f)
                    mv[f][u] = *(const float4*)(mbase + (size_t)(qw + u * 16 + col) * S
                                                + (kt + 1) * 64 + f * 16 + quad * 4);
        }

        // ---- drain K/V(kt+1) into LDS[nxt]; then issue K/V(kt+2) loads ----
        if (kt + 1 < NT) {
            const int nxt = cur ^ 1;
            *(bf16x8*)&Ks[nxt][srow * KSd + sc8] = kp;
            *(bf16x8*)&Vt[nxt][srow * KSd + sc8] = vp;
            if (kt + 2 < NT) {
                kp = *(const bf16x8*)(Kbase + (size_t)((kt + 2) * 64 + srow) * Dh + sc8);
                vp = *(const bf16x8*)(Vbase + (size_t)srow * S + (kt + 2) * 64 + sc8);
            }
        }

        // wave-private Ps write->read ordering (same-wave): LDS wait + fence.
        asm volatile("s_waitcnt lgkmcnt(0)" ::: "memory");
        __builtin_amdgcn_sched_barrier(0);

        // ---- O^T += V^T · P̃ ----
        #pragma unroll
        for (int kc = 0; kc < 2; ++kc) {
            bf16x8 pb[2];
            #pragma unroll
            for (int u = 0; u < 2; ++u)
                pb[u] = *(const bf16x8*)&pw[(u * 16 + col) * KSd + kc * 32 + quad * 8];
            #pragma unroll
            for (int g = 0; g < 4; ++g) {
                const bf16x8 va = *(const bf16x8*)&Vt[cur][(g * 16 + col) * KSd + kc * 32 + quad * 8];
                #pragma unroll
                for (int u = 0; u < 2; ++u)
                    o[g][u] = __builtin_amdgcn_mfma_f32_16x16x32_bf16(va, pb[u], o[g][u], 0, 0, 0);
            }
        }
        // tile-boundary barrier: LDS-only wait; mask/KV prefetch stays in
        // flight (they complete via compiler-counted vmcnt at use sites).
        lds_barrier();
    }

    // ---- deferred l reduction (quads hold disjoint key subsets) ----
    #pragma unroll
    for (int u = 0; u < 2; ++u) {
        lsum[u] += __shfl_xor(lsum[u], 16, 64);
        lsum[u] += __shfl_xor(lsum[u], 32, 64);
    }

    // ---- epilogue: lane (quad,r,col) holds O[q=qw+u*16+col][d=g*16+quad*4+r]
    #pragma unroll
    for (int u = 0; u < 2; ++u) {
        const float inv = 1.f / lsum[u];
        float* op = out + ((size_t)b * S + qw + u * 16 + col) * DM + h * Dh + quad * 4;
        #pragma unroll
        for (int g = 0; g < 4; ++g) {
            float4 ov;
            ov.x = o[g][u][0] * inv; ov.y = o[g][u][1] * inv;
            ov.z = o[g][u][2] * inv; ov.w = o[g][u][3] * inv;
            *(float4*)(op + g * 16) = ov;
        }
    }
}

// ---------------------------------------------------------------------------
extern "C" void kernel_launch(void* const* d_in, const int* in_sizes, int n_in,
                              void* d_out, int out_size, void* d_ws, size_t ws_size,
                              hipStream_t stream) {
    const float* hs   = (const float*)d_in[0];  // (B,S,DM)
    const float* mask = (const float*)d_in[1];  // (B,1,S,S)
    const int*   pos  = (const int*)  d_in[2];  // (B,S)
    const float* Wq   = (const float*)d_in[3];
    const float* Wk   = (const float*)d_in[4];
    const float* Wv   = (const float*)d_in[5];
    float* out = (float*)d_out;

    // workspace (ushort units): Xb 4,194,304 | Wb 3,145,728 |
    //   Qb,Kb [B,H,S,Dh], Vb [B,H,Dh,S] each 4,194,304 | Tab 1 MB (float2)
    unsigned short* Xb = (unsigned short*)d_ws;
    unsigned short* Wb = Xb + 4194304;
    unsigned short* Qb = Wb + 3145728;
    unsigned short* Kb = Qb + 4194304;
    unsigned short* Vb = Kb + 4194304;
    float*          Tab = (float*)(Vb + 4194304);   // 262144 floats

    cast_kernel<<<7168, 256, 0, stream>>>(hs, Wq, Wk, Wv, Xb, Wb);
    rope_tab_kernel<<<512, 256, 0, stream>>>(pos, Tab);
    qkv_gemm<<<dim3(32, 24), 256, 0, stream>>>(Xb, Wb, Tab, Qb, Kb, Vb);
    attn_kernel<<<dim3(S / 256, BH), 512, 0, stream>>>(Qb, Kb, Vb, mask, out);
}

// Round 10
// 228.070 us; speedup vs baseline: 1.3736x; 1.0147x over previous
//
#include <hip/hip_runtime.h>
#include <math.h>

// Problem constants (from reference)
#define B  2
#define S  2048
#define DM 1024
#define H  16
#define Dh 64
#define BH (B*H)

typedef short  bf16x8 __attribute__((ext_vector_type(8)));
typedef float  f32x4  __attribute__((ext_vector_type(4)));

__device__ __forceinline__ unsigned short f2bf(float f) {
    unsigned u = __float_as_uint(f);
    u = (u + 0x7fffu + ((u >> 16) & 1u)) >> 16;   // RNE, no NaN inputs here
    return (unsigned short)u;
}

// gfx950 packed f32->bf16 (RNE) — one VALU op for two converts+pack.
__device__ __forceinline__ unsigned cvt_pk_bf16(float lo, float hi) {
    unsigned r;
    asm("v_cvt_pk_bf16_f32 %0, %1, %2" : "=v"(r) : "v"(lo), "v"(hi));
    return r;
}

// Barrier that waits ONLY on LDS ops (lgkmcnt), leaving global-load / gload_lds
// prefetch in flight across the barrier. Two-sided compiler fence REQUIRED
// (R6 failure: s_barrier is IntrNoMem; without the trailing fence, post-
// barrier LDS ops hoist between the waitcnt and the barrier).
__device__ __forceinline__ void lds_barrier() {
    asm volatile("s_waitcnt lgkmcnt(0)" ::: "memory");
    __builtin_amdgcn_s_barrier();
    asm volatile("" ::: "memory");
}

// ---------------------------------------------------------------------------
// Kernel 0a: cast hidden_states + Wq|Wk|Wv (fp32) to bf16 workspace buffers.
// ---------------------------------------------------------------------------
__global__ __launch_bounds__(256) void cast_kernel(const float* __restrict__ X,
                                                   const float* __restrict__ Wq,
                                                   const float* __restrict__ Wk,
                                                   const float* __restrict__ Wv,
                                                   unsigned short* __restrict__ Xb,
                                                   unsigned short* __restrict__ Wb) {
    const long c = (long)(blockIdx.x * 256 + threadIdx.x) * 4;
    const float* src;
    unsigned short* dst;
    if (c < 4194304L) {
        src = X + c;  dst = Xb + c;
    } else {
        const long c2 = c - 4194304L;
        const int  wi = (int)(c2 >> 20);
        const long r  = c2 & 1048575L;
        src = (wi == 0 ? Wq : (wi == 1 ? Wk : Wv)) + r;
        dst = Wb + c2;
    }
    const float4 v = *(const float4*)src;
    ushort4 o;
    o.x = f2bf(v.x); o.y = f2bf(v.y); o.z = f2bf(v.z); o.w = f2bf(v.w);
    *(ushort4*)dst = o;
}

// ---------------------------------------------------------------------------
// Kernel 0b: RoPE cos/sin table: Tab[(b*S+s)*32 + i] = (cos, sin) of
//   pos[b,s] * 10000^(-i/32).  1 MB, L2-resident.
// ---------------------------------------------------------------------------
__global__ __launch_bounds__(256) void rope_tab_kernel(const int* __restrict__ pos,
                                                       float* __restrict__ Tab) {
    const int idx = blockIdx.x * 256 + threadIdx.x;   // < B*S*32 = 131072
    const int i  = idx & 31;
    const int bs = idx >> 5;
    const float p   = (float)pos[bs];
    const float inv = exp2f(-(float)i * 0.41524101186092029f);  // log2(1e4)/32
    float sn, cs;
    sincosf(p * inv, &sn, &cs);
    ((float2*)Tab)[idx] = make_float2(cs, sn);
}

// async global->LDS, 16B per lane; LDS dest = WAVE-UNIFORM base + lane*16.
__device__ __forceinline__ void gload_lds16(const unsigned short* g, unsigned short* l) {
    __builtin_amdgcn_global_load_lds(
        (const __attribute__((address_space(1))) unsigned int*)g,
        (__attribute__((address_space(3))) unsigned int*)l,
        16, 0, 0);
}

// ---------------------------------------------------------------------------
// Kernel 1: fused QKV GEMM — REWRITTEN this round: 256x256 tile, 512 thr
//   (8 waves = 2m x 4n, each owning 128x64 out), BK=64, double-buffered LDS
//   with counted vmcnt(8) (T3/T4 "minimum 2-phase" recipe): 64 MFMA per
//   barrier-pair per wave (was 16 with full vmcnt(0) drain — the measured
//   ~300 TF / 12%-of-peak bottleneck). T2 bank swizzle for 128B rows:
//   LDS[row][slot] holds global chunk slot^(row&7) (pre-swizzled SOURCE,
//   linear dest — m104/m173 discipline); frag reads apply the same XOR.
//   Grid 16x12 = 192 blocks (75% CU util, accepted for >=2x per-block gain).
//   Epilogue: 4 slices of 64 rows (Q/K) / 64 d (V) through Es (reuses As
//   LDS region) so all global stores stay coalesced 16B; RoPE via table.
// ---------------------------------------------------------------------------
__global__ __launch_bounds__(512, 2) void qkv_gemm(const unsigned short* __restrict__ Xb,
                                                   const unsigned short* __restrict__ Wb,
                                                   const float* __restrict__ Tab,
                                                   unsigned short* __restrict__ Qb,
                                                   unsigned short* __restrict__ Kb,
                                                   unsigned short* __restrict__ Vb) {
    __shared__ __align__(16) unsigned short As[2][256 * 64];   // 64 KB
    __shared__ __align__(16) unsigned short Bs[2][256 * 64];   // 64 KB

    const int tid  = threadIdx.x;
    const int w    = tid >> 6;                 // 0..7
    const int lane = tid & 63;
    const int col  = lane & 15;
    const int quad = lane >> 4;
    const int wr   = w >> 2;                   // 0..1  (m: wr*128)
    const int wn   = w & 3;                    // 0..3  (n: wn*64)
    const int m0 = blockIdx.x * 256;
    const int n0 = blockIdx.y * 256;

    f32x4 acc[8][4] = {};                      // 128 VGPRs

// stage K-tile T (k = T*64) into LDS buffer BUF: 4 A-chunks + 4 B-chunks
// per thread. cid = a*512 + tid covers (row = cid>>3, slot = cid&7);
// SOURCE chunk = slot ^ (row&7)  (T2 swizzle via pre-swizzled global src;
// dest stays linear as gload_lds requires: wave-uniform base + lane*16).
#define QKV_STAGE(BUF, T) do {                                                 \
    const int kk_ = (T) * 64;                                                  \
    unsigned short* Ab_ = &As[BUF][(w * 64) * 8];                              \
    unsigned short* Bb_ = &Bs[BUF][(w * 64) * 8];                              \
    _Pragma("unroll")                                                          \
    for (int a_ = 0; a_ < 4; ++a_) {                                           \
        const int cid_ = a_ * 512 + tid;                                       \
        const int row_ = cid_ >> 3;                                            \
        const int gof_ = ((cid_ & 7) ^ (row_ & 7)) << 3;                       \
        gload_lds16(Xb + (size_t)(m0 + row_) * 1024 + kk_ + gof_,              \
                    Ab_ + a_ * 4096);                                          \
        gload_lds16(Wb + (size_t)(n0 + row_) * 1024 + kk_ + gof_,              \
                    Bb_ + a_ * 4096);                                          \
    }                                                                          \
} while (0)

    // prologue: tiles 0 and 1 in flight (16 outstanding gloads/thread)
    QKV_STAGE(0, 0);
    QKV_STAGE(1, 1);

    for (int t = 0; t < 16; ++t) {
        const int cb = t & 1;
        // own stage(t) complete (stage(t+1) stays in flight) — counted wait.
        if (t < 15) asm volatile("s_waitcnt vmcnt(8)" ::: "memory");
        else        asm volatile("s_waitcnt vmcnt(0)" ::: "memory");
        lds_barrier();     // all waves' stage(t) confirmed -> safe to read

        const unsigned short* Ac = &As[cb][0];
        const unsigned short* Bc = &Bs[cb][0];
        #pragma unroll
        for (int kc = 0; kc < 2; ++kc) {
            bf16x8 af[8], bfr[4];
            #pragma unroll
            for (int i = 0; i < 8; ++i) {
                const int row = wr * 128 + i * 16 + col;
                const int sl  = ((kc * 4 + quad) ^ (row & 7)) * 8;
                af[i] = *(const bf16x8*)&Ac[row * 64 + sl];
            }
            #pragma unroll
            for (int j = 0; j < 4; ++j) {
                const int row = wn * 64 + j * 16 + col;
                const int sl  = ((kc * 4 + quad) ^ (row & 7)) * 8;
                bfr[j] = *(const bf16x8*)&Bc[row * 64 + sl];
            }
            #pragma unroll
            for (int i = 0; i < 8; ++i)
                #pragma unroll
                for (int j = 0; j < 4; ++j)
                    acc[i][j] = __builtin_amdgcn_mfma_f32_16x16x32_bf16(af[i], bfr[j], acc[i][j], 0, 0, 0);
        }

        lds_barrier();     // protect buf[cb] until ALL waves done reading
        if (t + 2 < 16) QKV_STAGE(cb, t + 2);   // restage the consumed buffer
    }
#undef QKV_STAGE

    // ---- epilogue: C[m = wr*128+i*16+quad*4+r][n = wn*64+j*16+col] ----
    unsigned short* Es = (unsigned short*)&As[0][0];   // reuse (34 KB < 64 KB)
    const int wsel = n0 >> 10;                 // 0=Q, 1=K, 2=V
    const int hh0  = (n0 & 1023) >> 6;         // base head (4 heads per tile)
    const int bb2  = m0 >> 11;                 // batch (256 | 2048: no straddle)
    const int ssb  = m0 & 2047;                // seq base

    if (wsel == 2) {
        // V -> [B,H,Dh,S]; slice s = one 64-wide d-block = wave-column wn==s
        #pragma unroll
        for (int s = 0; s < 4; ++s) {
            if (wn == s) {
                #pragma unroll
                for (int i = 0; i < 8; ++i) {
                    const int sl = wr * 128 + i * 16 + quad * 4;
                    #pragma unroll
                    for (int j = 0; j < 4; ++j) {
                        const int dl = j * 16 + col;
                        ushort4 ov;
                        ov.x = f2bf(acc[i][j][0]); ov.y = f2bf(acc[i][j][1]);
                        ov.z = f2bf(acc[i][j][2]); ov.w = f2bf(acc[i][j][3]);
                        *(ushort4*)&Es[dl * 264 + sl] = ov;
                    }
                }
            }
            lds_barrier();
            #pragma unroll
            for (int k = 0; k < 4; ++k) {
                const int c  = tid + k * 512;
                const int dl = c >> 5;               // 0..63
                const int s8 = (c & 31) * 8;         // 0..248
                *(bf16x8*)(Vb + ((size_t)(bb2 * H + hh0 + s) * Dh + dl) * S + ssb + s8)
                    = *(const bf16x8*)&Es[dl * 264 + s8];
            }
            lds_barrier();
        }
    } else {
        // Q/K with fused RoPE; slice s = 64 m-rows, written by waves wr==s>>1
        unsigned short* dp = (wsel == 0) ? Qb : Kb;
        const float qscale = (wsel == 0) ? 0.125f : 1.0f;   // D^-0.5 for Q
        #pragma unroll
        for (int s = 0; s < 4; ++s) {
            if (wr == (s >> 1)) {
                const int io = (s & 1) * 4;
                #pragma unroll
                for (int i2 = 0; i2 < 4; ++i2) {
                    #pragma unroll
                    for (int r = 0; r < 4; ++r) {
                        const int rl = i2 * 16 + quad * 4 + r;     // 0..63
                        const int ss = ssb + s * 64 + rl;
                        const float2 t0 = ((const float2*)Tab)[(size_t)(bb2 * S + ss) * 32 + col];
                        const float2 t1 = ((const float2*)Tab)[(size_t)(bb2 * S + ss) * 32 + col + 16];
                        const float a0 = acc[io + i2][0][r] * qscale;
                        const float a1 = acc[io + i2][1][r] * qscale;
                        const float a2 = acc[io + i2][2][r] * qscale;
                        const float a3 = acc[io + i2][3][r] * qscale;
                        unsigned short* e = &Es[rl * 264 + wn * 64];
                        e[col]      = f2bf(a0 * t0.x - a2 * t0.y);
                        e[col + 16] = f2bf(a1 * t1.x - a3 * t1.y);
                        e[col + 32] = f2bf(a2 * t0.x + a0 * t0.y);
                        e[col + 48] = f2bf(a3 * t1.x + a1 * t1.y);
                    }
                }
            }
            lds_barrier();
            #pragma unroll
            for (int k = 0; k < 4; ++k) {
                const int c  = tid + k * 512;
                const int rl = c >> 5;               // 0..63
                const int c8 = (c & 31) * 8;         // 0..248
                *(bf16x8*)(dp + ((size_t)(bb2 * H + hh0 + (c8 >> 6)) * S
                                 + ssb + s * 64 + rl) * Dh + (c8 & 63))
                    = *(const bf16x8*)&Es[rl * 264 + c8];
            }
            lds_barrier();
        }
    }
}

// ---------------------------------------------------------------------------
// Kernel 2: flash attention — R7 verified version (best attn: 87.0 µs).
//   Counted-wait barriers (two-sided-fence lds_barrier), mask(kt+1)/KV(kt+2)
//   register prefetch, LDS K/V staging for coalescing.
//   grid = (S/128, B*H) = 512 blocks, 256 thr.
// ---------------------------------------------------------------------------
#define KSd 72
#define LOG2E  1.4426950408889634f
#define NEG8L (-11.541560327111707f)      // -8 * log2(e); exp(s-8) == exp2(fma)
#define NT (S / 64)

__global__ __launch_bounds__(256) void attn_kernel(const unsigned short* __restrict__ Q,
                                                   const unsigned short* __restrict__ K,
                                                   const unsigned short* __restrict__ V,
                                                   const float* __restrict__ mask,
                                                   float* __restrict__ out) {
    __shared__ __align__(16) unsigned short Ks[2][64 * KSd];   // [key][d]
    __shared__ __align__(16) unsigned short Vt[2][64 * KSd];   // [d][key]
    __shared__ __align__(16) unsigned short Ps[4 * 32 * KSd];

    const int tid  = threadIdx.x;
    const int w    = tid >> 6;
    const int lane = tid & 63;
    const int col  = lane & 15;
    const int quad = lane >> 4;
    const int bh   = blockIdx.y;
    const int b    = bh >> 4, h = bh & 15;
    const int q0   = blockIdx.x * 128;
    const int qw   = q0 + w * 32;             // wave's q base (32 rows)

    const int srow = tid >> 3;            // 0..31
    const int sc8  = (tid & 7) * 8;

    // Q fragments: qa[u][kc] — lane holds Q[q=qw+u*16+col][kc*32+quad*8 ..+7]
    bf16x8 qa[2][2];
    #pragma unroll
    for (int u = 0; u < 2; ++u) {
        const unsigned short* qrow = Q + ((size_t)bh * S + qw + u * 16 + col) * Dh;
        qa[u][0] = *(const bf16x8*)(qrow + quad * 8);
        qa[u][1] = *(const bf16x8*)(qrow + 32 + quad * 8);
    }

    f32x4 o[4][2] = {};                        // O^T frags: [d-frag g][q-frag u]
    float lsum[2] = {0.f, 0.f};
    const float* mbase = mask + (size_t)b * S * S;
    unsigned short* pw = Ps + w * 32 * KSd;
    const unsigned short* Kbase = K + (size_t)bh * S * Dh;
    const unsigned short* Vbase = V + (size_t)bh * Dh * S;   // transposed

    // ---- prologue: tile0 K/V + mask(tile0) into regs; stage tile0 to LDS
    //      buffer 0; then pre-issue tile1 K/V loads (drained at kt=0). ----
    bf16x8 kp[2], vp[2];
    float4 mv[4][2];
    #pragma unroll
    for (int cc = 0; cc < 2; ++cc) {
        kp[cc] = *(const bf16x8*)(Kbase + (size_t)(srow + cc * 32) * Dh + sc8);
        vp[cc] = *(const bf16x8*)(Vbase + (size_t)(srow + cc * 32) * S + sc8);
    }
    #pragma unroll
    for (int u = 0; u < 2; ++u)
        #pragma unroll
        for (int f = 0; f < 4; ++f)
            mv[f][u] = *(const float4*)(mbase + (size_t)(qw + u * 16 + col) * S
                                        + f * 16 + quad * 4);
    #pragma unroll
    for (int cc = 0; cc < 2; ++cc) {
        const int row = srow + cc * 32;
        *(bf16x8*)&Ks[0][row * KSd + sc8] = kp[cc];
        *(bf16x8*)&Vt[0][row * KSd + sc8] = vp[cc];
    }
    #pragma unroll
    for (int cc = 0; cc < 2; ++cc) {        // issue tile1 (stays in flight)
        kp[cc] = *(const bf16x8*)(Kbase + (size_t)(64 + srow + cc * 32) * Dh + sc8);
        vp[cc] = *(const bf16x8*)(Vbase + (size_t)(srow + cc * 32) * S + 64 + sc8);
    }
    lds_barrier();

    for (int kt = 0; kt < NT; ++kt) {
        const int cur = kt & 1;

        // ---- S^T = K · Q^T : C[m=key][n=q] ----
        f32x4 sc[4][2] = {};
        #pragma unroll
        for (int f = 0; f < 4; ++f) {
            const bf16x8 ka0 = *(const bf16x8*)&Ks[cur][(f * 16 + col) * KSd + quad * 8];
            const bf16x8 ka1 = *(const bf16x8*)&Ks[cur][(f * 16 + col) * KSd + 32 + quad * 8];
            #pragma unroll
            for (int u = 0; u < 2; ++u) {
                sc[f][u] = __builtin_amdgcn_mfma_f32_16x16x32_bf16(ka0, qa[u][0], sc[f][u], 0, 0, 0);
                sc[f][u] = __builtin_amdgcn_mfma_f32_16x16x32_bf16(ka1, qa[u][1], sc[f][u], 0, 0, 0);
            }
        }

        // ---- static-shift softmax numerator + packed P̃ store (consumes mv) ----
        #pragma unroll
        for (int u = 0; u < 2; ++u) {
            #pragma unroll
            for (int f = 0; f < 4; ++f) {
                sc[f][u][0] += mv[f][u].x; sc[f][u][1] += mv[f][u].y;
                sc[f][u][2] += mv[f][u].z; sc[f][u][3] += mv[f][u].w;
            }
            #pragma unroll
            for (int f = 0; f < 4; ++f)
                #pragma unroll
                for (int r = 0; r < 4; ++r) {
                    const float pv = __builtin_amdgcn_exp2f(
                        __builtin_fmaf(sc[f][u][r], LOG2E, NEG8L));
                    sc[f][u][r] = pv;
                    lsum[u] += pv;
                }
            unsigned short* pq = pw + (u * 16 + col) * KSd;
            #pragma unroll
            for (int f = 0; f < 4; ++f) {
                *(uint2*)&pq[f * 16 + quad * 4] =
                    make_uint2(cvt_pk_bf16(sc[f][u][0], sc[f][u][1]),
                               cvt_pk_bf16(sc[f][u][2], sc[f][u][3]));
            }
        }

        // ---- mv dead: issue mask loads for tile kt+1 directly into mv ----
        if (kt + 1 < NT) {
            #pragma unroll
            for (int u = 0; u < 2; ++u)
                #pragma unroll
                for (int f = 0; f < 4; ++f)
                    mv[f][u] = *(const float4*)(mbase + (size_t)(qw + u * 16 + col) * S
                                                + (kt + 1) * 64 + f * 16 + quad * 4);
        }

        // ---- drain K/V(kt+1) into LDS[nxt]; then issue K/V(kt+2) loads ----
        if (kt + 1 < NT) {
            const int nxt = cur ^ 1;
            #pragma unroll
            for (int cc = 0; cc < 2; ++cc) {
                const int row = srow + cc * 32;
                *(bf16x8*)&Ks[nxt][row * KSd + sc8] = kp[cc];
                *(bf16x8*)&Vt[nxt][row * KSd + sc8] = vp[cc];
            }
            if (kt + 2 < NT) {
                #pragma unroll
                for (int cc = 0; cc < 2; ++cc) {
                    kp[cc] = *(const bf16x8*)(Kbase + (size_t)((kt + 2) * 64 + srow + cc * 32) * Dh + sc8);
                    vp[cc] = *(const bf16x8*)(Vbase + (size_t)(srow + cc * 32) * S + (kt + 2) * 64 + sc8);
                }
            }
        }

        // wave-private Ps write->read ordering (same-wave): LDS wait + fence.
        asm volatile("s_waitcnt lgkmcnt(0)" ::: "memory");
        __builtin_amdgcn_sched_barrier(0);

        // ---- O^T += V^T · P̃ ----
        #pragma unroll
        for (int kc = 0; kc < 2; ++kc) {
            bf16x8 pb[2];
            #pragma unroll
            for (int u = 0; u < 2; ++u)
                pb[u] = *(const bf16x8*)&pw[(u * 16 + col) * KSd + kc * 32 + quad * 8];
            #pragma unroll
            for (int g = 0; g < 4; ++g) {
                const bf16x8 va = *(const bf16x8*)&Vt[cur][(g * 16 + col) * KSd + kc * 32 + quad * 8];
                #pragma unroll
                for (int u = 0; u < 2; ++u)
                    o[g][u] = __builtin_amdgcn_mfma_f32_16x16x32_bf16(va, pb[u], o[g][u], 0, 0, 0);
            }
        }
        // tile-boundary barrier: LDS-only wait; mask/KV prefetch stays in
        // flight (they complete via compiler-counted vmcnt at use sites).
        lds_barrier();
    }

    // ---- deferred l reduction (quads hold disjoint key subsets) ----
    #pragma unroll
    for (int u = 0; u < 2; ++u) {
        lsum[u] += __shfl_xor(lsum[u], 16, 64);
        lsum[u] += __shfl_xor(lsum[u], 32, 64);
    }

    // ---- epilogue: lane (quad,r,col) holds O[q=qw+u*16+col][d=g*16+quad*4+r]
    #pragma unroll
    for (int u = 0; u < 2; ++u) {
        const float inv = 1.f / lsum[u];
        float* op = out + ((size_t)b * S + qw + u * 16 + col) * DM + h * Dh + quad * 4;
        #pragma unroll
        for (int g = 0; g < 4; ++g) {
            float4 ov;
            ov.x = o[g][u][0] * inv; ov.y = o[g][u][1] * inv;
            ov.z = o[g][u][2] * inv; ov.w = o[g][u][3] * inv;
            *(float4*)(op + g * 16) = ov;
        }
    }
}

// ---------------------------------------------------------------------------
extern "C" void kernel_launch(void* const* d_in, const int* in_sizes, int n_in,
                              void* d_out, int out_size, void* d_ws, size_t ws_size,
                              hipStream_t stream) {
    const float* hs   = (const float*)d_in[0];  // (B,S,DM)
    const float* mask = (const float*)d_in[1];  // (B,1,S,S)
    const int*   pos  = (const int*)  d_in[2];  // (B,S)
    const float* Wq   = (const float*)d_in[3];
    const float* Wk   = (const float*)d_in[4];
    const float* Wv   = (const float*)d_in[5];
    float* out = (float*)d_out;

    // workspace (ushort units): Xb 4,194,304 | Wb 3,145,728 |
    //   Qb,Kb [B,H,S,Dh], Vb [B,H,Dh,S] each 4,194,304 | Tab 1 MB (float2)
    unsigned short* Xb = (unsigned short*)d_ws;
    unsigned short* Wb = Xb + 4194304;
    unsigned short* Qb = Wb + 3145728;
    unsigned short* Kb = Qb + 4194304;
    unsigned short* Vb = Kb + 4194304;
    float*          Tab = (float*)(Vb + 4194304);   // 262144 floats

    cast_kernel<<<7168, 256, 0, stream>>>(hs, Wq, Wk, Wv, Xb, Wb);
    rope_tab_kernel<<<512, 256, 0, stream>>>(pos, Tab);
    qkv_gemm<<<dim3(16, 12), 512, 0, stream>>>(Xb, Wb, Tab, Qb, Kb, Vb);
    attn_kernel<<<dim3(S / 128, BH), 256, 0, stream>>>(Qb, Kb, Vb, mask, out);
}

// Round 11
// 226.429 us; speedup vs baseline: 1.3836x; 1.0072x over previous
//
#include <hip/hip_runtime.h>
#include <math.h>

// Problem constants (from reference)
#define B  2
#define S  2048
#define DM 1024
#define H  16
#define Dh 64
#define BH (B*H)

typedef short  bf16x8 __attribute__((ext_vector_type(8)));
typedef float  f32x4  __attribute__((ext_vector_type(4)));

__device__ __forceinline__ unsigned short f2bf(float f) {
    unsigned u = __float_as_uint(f);
    u = (u + 0x7fffu + ((u >> 16) & 1u)) >> 16;   // RNE, no NaN inputs here
    return (unsigned short)u;
}

// gfx950 packed f32->bf16 (RNE) — one VALU op for two converts+pack.
__device__ __forceinline__ unsigned cvt_pk_bf16(float lo, float hi) {
    unsigned r;
    asm("v_cvt_pk_bf16_f32 %0, %1, %2" : "=v"(r) : "v"(lo), "v"(hi));
    return r;
}

// Barrier that waits ONLY on LDS ops (lgkmcnt), leaving global-load register
// prefetch in flight across the barrier. Two-sided compiler fence REQUIRED
// (R6 failure: s_barrier is IntrNoMem; without the trailing fence, post-
// barrier LDS reads hoist between the waitcnt and the barrier).
__device__ __forceinline__ void lds_barrier() {
    asm volatile("s_waitcnt lgkmcnt(0)" ::: "memory");
    __builtin_amdgcn_s_barrier();
    asm volatile("" ::: "memory");
}

// ---------------------------------------------------------------------------
// Kernel 0 (FUSED): blocks [0,7168): cast hidden_states + Wq|Wk|Wv to bf16.
//   Blocks [7168,7680): RoPE cos/sin table Tab[(b*S+s)*32+i] = (cos,sin) of
//   pos[b,s] * 10000^(-i/32) (1 MB, L2-resident). Fusion removes one
//   kernel-launch boundary (~30 µs of the budget is inter-kernel gaps).
// ---------------------------------------------------------------------------
__global__ __launch_bounds__(256) void cast_rope_kernel(const float* __restrict__ X,
                                                        const float* __restrict__ Wq,
                                                        const float* __restrict__ Wk,
                                                        const float* __restrict__ Wv,
                                                        const int* __restrict__ pos,
                                                        unsigned short* __restrict__ Xb,
                                                        unsigned short* __restrict__ Wb,
                                                        float* __restrict__ Tab) {
    if (blockIdx.x < 7168) {
        const long c = (long)(blockIdx.x * 256 + threadIdx.x) * 4;
        const float* src;
        unsigned short* dst;
        if (c < 4194304L) {
            src = X + c;  dst = Xb + c;
        } else {
            const long c2 = c - 4194304L;
            const int  wi = (int)(c2 >> 20);
            const long r  = c2 & 1048575L;
            src = (wi == 0 ? Wq : (wi == 1 ? Wk : Wv)) + r;
            dst = Wb + c2;
        }
        const float4 v = *(const float4*)src;
        ushort4 o;
        o.x = f2bf(v.x); o.y = f2bf(v.y); o.z = f2bf(v.z); o.w = f2bf(v.w);
        *(ushort4*)dst = o;
    } else {
        const int idx = (blockIdx.x - 7168) * 256 + threadIdx.x;   // < 131072
        const int i  = idx & 31;
        const int bs = idx >> 5;
        const float p   = (float)pos[bs];
        const float inv = exp2f(-(float)i * 0.41524101186092029f);  // log2(1e4)/32
        float sn, cs;
        sincosf(p * inv, &sn, &cs);
        ((float2*)Tab)[idx] = make_float2(cs, sn);
    }
}

// async global->LDS, 16B per lane
__device__ __forceinline__ void gload_lds16(const unsigned short* g, unsigned short* l) {
    __builtin_amdgcn_global_load_lds(
        (const __attribute__((address_space(1))) unsigned int*)g,
        (__attribute__((address_space(3))) unsigned int*)l,
        16, 0, 0);
}

// ---------------------------------------------------------------------------
// Kernel 1: fused QKV GEMM (R0/R7 verified config: 128² tile, BK=32,
//   16 MFMA/barrier — BK=64 (R3), 256² 2-phase (R10) and XCD swizzle (R9)
//   all regressed; ~300 TF is ON m102's shape curve for 2048-class shapes).
//   global_load_lds staging with XOR chunk swizzle. Epilogue: RoPE via
//   table + LDS round-trip (Es) so ALL global stores are coalesced 16B.
//   V written transposed [B,H,Dh,S].
// ---------------------------------------------------------------------------
__global__ __launch_bounds__(256) void qkv_gemm(const unsigned short* __restrict__ Xb,
                                                const unsigned short* __restrict__ Wb,
                                                const float* __restrict__ Tab,
                                                unsigned short* __restrict__ Qb,
                                                unsigned short* __restrict__ Kb,
                                                unsigned short* __restrict__ Vb) {
    __shared__ __align__(16) unsigned short As[128 * 32];
    __shared__ __align__(16) unsigned short Bs[128 * 32];
    __shared__ __align__(16) unsigned short Es[64 * 136];   // epilogue staging

    const int tid  = threadIdx.x;
    const int w    = tid >> 6;
    const int lane = tid & 63;
    const int col  = lane & 15;
    const int quad = lane >> 4;
    const int m0 = blockIdx.x * 128;
    const int n0 = blockIdx.y * 128;
    const int mw = (w & 1) * 64;
    const int nw = (w >> 1) * 64;

    // staging: lane i loads row i>>2, global chunk (i&3)^(row&3)  (XOR swizzle)
    const int srow = lane >> 2;
    const int sk8  = (((lane & 3) ^ (srow & 3))) * 8;

    f32x4 acc[4][4] = {};

    for (int k0 = 0; k0 < 1024; k0 += 32) {
        __syncthreads();
        #pragma unroll
        for (int it = 0; it < 2; ++it) {
            const int rbase = w * 16 + it * 64;
            gload_lds16(Xb + (size_t)(m0 + rbase + srow) * 1024 + k0 + sk8,
                        &As[rbase * 32]);
            gload_lds16(Wb + (size_t)(n0 + rbase + srow) * 1024 + k0 + sk8,
                        &Bs[rbase * 32]);
        }
        __syncthreads();

        // global k-chunk quad lives at LDS slot quad^(row&3); row&3 == col&3
        const int fs = (quad ^ (col & 3)) * 8;
        bf16x8 a[4], bb[4];
        #pragma unroll
        for (int i = 0; i < 4; ++i)
            a[i] = *(const bf16x8*)&As[(mw + i * 16 + col) * 32 + fs];
        #pragma unroll
        for (int j = 0; j < 4; ++j)
            bb[j] = *(const bf16x8*)&Bs[(nw + j * 16 + col) * 32 + fs];
        #pragma unroll
        for (int i = 0; i < 4; ++i)
            #pragma unroll
            for (int j = 0; j < 4; ++j)
                acc[i][j] = __builtin_amdgcn_mfma_f32_16x16x32_bf16(a[i], bb[j], acc[i][j], 0, 0, 0);
    }

    // ---- epilogue ----
    const int wsel = n0 >> 10;                 // 0=Q, 1=K, 2=V
    const int hh0  = (n0 & 1023) >> 6;         // base head of this n-tile
    const int bb2  = m0 >> 11;                 // batch (block never straddles)
    const int ssb  = m0 & 2047;                // seq base

    if (wsel == 2) {
        // V -> [B,H,Dh,S]; Es[dl][ssl] per dcol-half, b64 packed writes
        #pragma unroll
        for (int half = 0; half < 2; ++half) {
            __syncthreads();
            if ((w >> 1) == half) {            // waves whose nw == half*64
                #pragma unroll
                for (int i = 0; i < 4; ++i) {
                    const int sl = mw + i * 16 + quad * 4;
                    #pragma unroll
                    for (int j = 0; j < 4; ++j) {
                        const int dl = j * 16 + col;     // 0..63 within half
                        ushort4 ov;
                        ov.x = f2bf(acc[i][j][0]); ov.y = f2bf(acc[i][j][1]);
                        ov.z = f2bf(acc[i][j][2]); ov.w = f2bf(acc[i][j][3]);
                        *(ushort4*)&Es[dl * 136 + sl] = ov;
                    }
                }
            }
            __syncthreads();
            #pragma unroll
            for (int k = 0; k < 4; ++k) {
                const int c  = tid + k * 256;
                const int dl = c >> 4;               // 0..63 within half
                const int s8 = (c & 15) * 8;
                const int d  = half * 64 + dl;
                const bf16x8 v = *(const bf16x8*)&Es[dl * 136 + s8];
                *(bf16x8*)(Vb + ((size_t)(bb2 * H + hh0 + (d >> 6)) * Dh + (d & 63)) * S
                           + ssb + s8) = v;
            }
        }
    } else {
        // Q/K with fused RoPE from table; Es[row][d] per m-half
        unsigned short* dp = (wsel == 0) ? Qb : Kb;
        const float qscale = (wsel == 0) ? 0.125f : 1.0f;   // D^-0.5 for Q
        #pragma unroll
        for (int half = 0; half < 2; ++half) {
            __syncthreads();
            if ((w & 1) == half) {             // waves whose mw == half*64
                #pragma unroll
                for (int i = 0; i < 4; ++i) {
                    #pragma unroll
                    for (int r = 0; r < 4; ++r) {
                        const int rl = i * 16 + quad * 4 + r;   // 0..63 local
                        const int ss = ssb + half * 64 + rl;
                        const float2 t0 = ((const float2*)Tab)[(size_t)(bb2 * S + ss) * 32 + col];
                        const float2 t1 = ((const float2*)Tab)[(size_t)(bb2 * S + ss) * 32 + col + 16];
                        const float a0 = acc[i][0][r] * qscale, a1 = acc[i][1][r] * qscale;
                        const float a2 = acc[i][2][r] * qscale, a3 = acc[i][3][r] * qscale;
                        unsigned short* e = &Es[rl * 136 + nw];
                        e[col]      = f2bf(a0 * t0.x - a2 * t0.y);
                        e[col + 16] = f2bf(a1 * t1.x - a3 * t1.y);
                        e[col + 32] = f2bf(a2 * t0.x + a0 * t0.y);
                        e[col + 48] = f2bf(a3 * t1.x + a1 * t1.y);
                    }
                }
            }
            __syncthreads();
            #pragma unroll
            for (int k = 0; k < 4; ++k) {
                const int c  = tid + k * 256;
                const int rl = c >> 4;               // 0..63 local row
                const int d8 = (c & 15) * 8;
                const bf16x8 v = *(const bf16x8*)&Es[rl * 136 + d8];
                *(bf16x8*)(dp + ((size_t)(bb2 * H + hh0 + (d8 >> 6)) * S
                                 + ssb + half * 64 + rl) * Dh + (d8 & 63)) = v;
            }
        }
    }
}

// ---------------------------------------------------------------------------
// Kernel 2: flash attention — R7 verified pipeline (counted-wait barriers,
//   mask(kt+1)/KV(kt+2) register prefetch, LDS K/V staging for coalescing)
//   + NEW: T5 s_setprio(1) around both MFMA clusters (catalog: +4-7% attn,
//   m191 — CUs host 2 blocks at independent phases, the regime where the
//   scheduler has something to arbitrate).
//   grid = (S/128, B*H) = 512 blocks, 256 thr.
// ---------------------------------------------------------------------------
#define KSd 72
#define LOG2E  1.4426950408889634f
#define NEG8L (-11.541560327111707f)      // -8 * log2(e); exp(s-8) == exp2(fma)
#define NT (S / 64)

__global__ __launch_bounds__(256) void attn_kernel(const unsigned short* __restrict__ Q,
                                                   const unsigned short* __restrict__ K,
                                                   const unsigned short* __restrict__ V,
                                                   const float* __restrict__ mask,
                                                   float* __restrict__ out) {
    __shared__ __align__(16) unsigned short Ks[2][64 * KSd];   // [key][d]
    __shared__ __align__(16) unsigned short Vt[2][64 * KSd];   // [d][key]
    __shared__ __align__(16) unsigned short Ps[4 * 32 * KSd];

    const int tid  = threadIdx.x;
    const int w    = tid >> 6;
    const int lane = tid & 63;
    const int col  = lane & 15;
    const int quad = lane >> 4;
    const int bh   = blockIdx.y;
    const int b    = bh >> 4, h = bh & 15;
    const int q0   = blockIdx.x * 128;
    const int qw   = q0 + w * 32;             // wave's q base (32 rows)

    const int srow = tid >> 3;            // 0..31
    const int sc8  = (tid & 7) * 8;

    // Q fragments: qa[u][kc] — lane holds Q[q=qw+u*16+col][kc*32+quad*8 ..+7]
    bf16x8 qa[2][2];
    #pragma unroll
    for (int u = 0; u < 2; ++u) {
        const unsigned short* qrow = Q + ((size_t)bh * S + qw + u * 16 + col) * Dh;
        qa[u][0] = *(const bf16x8*)(qrow + quad * 8);
        qa[u][1] = *(const bf16x8*)(qrow + 32 + quad * 8);
    }

    f32x4 o[4][2] = {};                        // O^T frags: [d-frag g][q-frag u]
    float lsum[2] = {0.f, 0.f};
    const float* mbase = mask + (size_t)b * S * S;
    unsigned short* pw = Ps + w * 32 * KSd;
    const unsigned short* Kbase = K + (size_t)bh * S * Dh;
    const unsigned short* Vbase = V + (size_t)bh * Dh * S;   // transposed

    // ---- prologue: tile0 K/V + mask(tile0) into regs; stage tile0 to LDS
    //      buffer 0; then pre-issue tile1 K/V loads (drained at kt=0). ----
    bf16x8 kp[2], vp[2];
    float4 mv[4][2];
    #pragma unroll
    for (int cc = 0; cc < 2; ++cc) {
        kp[cc] = *(const bf16x8*)(Kbase + (size_t)(srow + cc * 32) * Dh + sc8);
        vp[cc] = *(const bf16x8*)(Vbase + (size_t)(srow + cc * 32) * S + sc8);
    }
    #pragma unroll
    for (int u = 0; u < 2; ++u)
        #pragma unroll
        for (int f = 0; f < 4; ++f)
            mv[f][u] = *(const float4*)(mbase + (size_t)(qw + u * 16 + col) * S
                                        + f * 16 + quad * 4);
    #pragma unroll
    for (int cc = 0; cc < 2; ++cc) {
        const int row = srow + cc * 32;
        *(bf16x8*)&Ks[0][row * KSd + sc8] = kp[cc];
        *(bf16x8*)&Vt[0][row * KSd + sc8] = vp[cc];
    }
    #pragma unroll
    for (int cc = 0; cc < 2; ++cc) {        // issue tile1 (stays in flight)
        kp[cc] = *(const bf16x8*)(Kbase + (size_t)(64 + srow + cc * 32) * Dh + sc8);
        vp[cc] = *(const bf16x8*)(Vbase + (size_t)(srow + cc * 32) * S + 64 + sc8);
    }
    lds_barrier();

    for (int kt = 0; kt < NT; ++kt) {
        const int cur = kt & 1;

        // ---- S^T = K · Q^T : C[m=key][n=q] ----
        f32x4 sc[4][2] = {};
        __builtin_amdgcn_s_setprio(1);
        #pragma unroll
        for (int f = 0; f < 4; ++f) {
            const bf16x8 ka0 = *(const bf16x8*)&Ks[cur][(f * 16 + col) * KSd + quad * 8];
            const bf16x8 ka1 = *(const bf16x8*)&Ks[cur][(f * 16 + col) * KSd + 32 + quad * 8];
            #pragma unroll
            for (int u = 0; u < 2; ++u) {
                sc[f][u] = __builtin_amdgcn_mfma_f32_16x16x32_bf16(ka0, qa[u][0], sc[f][u], 0, 0, 0);
                sc[f][u] = __builtin_amdgcn_mfma_f32_16x16x32_bf16(ka1, qa[u][1], sc[f][u], 0, 0, 0);
            }
        }
        __builtin_amdgcn_s_setprio(0);

        // ---- static-shift softmax numerator + packed P̃ store (consumes mv) ----
        #pragma unroll
        for (int u = 0; u < 2; ++u) {
            #pragma unroll
            for (int f = 0; f < 4; ++f) {
                sc[f][u][0] += mv[f][u].x; sc[f][u][1] += mv[f][u].y;
                sc[f][u][2] += mv[f][u].z; sc[f][u][3] += mv[f][u].w;
            }
            #pragma unroll
            for (int f = 0; f < 4; ++f)
                #pragma unroll
                for (int r = 0; r < 4; ++r) {
                    const float pv = __builtin_amdgcn_exp2f(
                        __builtin_fmaf(sc[f][u][r], LOG2E, NEG8L));
                    sc[f][u][r] = pv;
                    lsum[u] += pv;
                }
            unsigned short* pq = pw + (u * 16 + col) * KSd;
            #pragma unroll
            for (int f = 0; f < 4; ++f) {
                *(uint2*)&pq[f * 16 + quad * 4] =
                    make_uint2(cvt_pk_bf16(sc[f][u][0], sc[f][u][1]),
                               cvt_pk_bf16(sc[f][u][2], sc[f][u][3]));
            }
        }

        // ---- mv dead: issue mask loads for tile kt+1 directly into mv ----
        if (kt + 1 < NT) {
            #pragma unroll
            for (int u = 0; u < 2; ++u)
                #pragma unroll
                for (int f = 0; f < 4; ++f)
                    mv[f][u] = *(const float4*)(mbase + (size_t)(qw + u * 16 + col) * S
                                                + (kt + 1) * 64 + f * 16 + quad * 4);
        }

        // ---- drain K/V(kt+1) into LDS[nxt]; then issue K/V(kt+2) loads ----
        if (kt + 1 < NT) {
            const int nxt = cur ^ 1;
            #pragma unroll
            for (int cc = 0; cc < 2; ++cc) {
                const int row = srow + cc * 32;
                *(bf16x8*)&Ks[nxt][row * KSd + sc8] = kp[cc];
                *(bf16x8*)&Vt[nxt][row * KSd + sc8] = vp[cc];
            }
            if (kt + 2 < NT) {
                #pragma unroll
                for (int cc = 0; cc < 2; ++cc) {
                    kp[cc] = *(const bf16x8*)(Kbase + (size_t)((kt + 2) * 64 + srow + cc * 32) * Dh + sc8);
                    vp[cc] = *(const bf16x8*)(Vbase + (size_t)(srow + cc * 32) * S + (kt + 2) * 64 + sc8);
                }
            }
        }

        // wave-private Ps write->read ordering (same-wave): LDS wait + fence.
        asm volatile("s_waitcnt lgkmcnt(0)" ::: "memory");
        __builtin_amdgcn_sched_barrier(0);

        // ---- O^T += V^T · P̃ ----
        __builtin_amdgcn_s_setprio(1);
        #pragma unroll
        for (int kc = 0; kc < 2; ++kc) {
            bf16x8 pb[2];
            #pragma unroll
            for (int u = 0; u < 2; ++u)
                pb[u] = *(const bf16x8*)&pw[(u * 16 + col) * KSd + kc * 32 + quad * 8];
            #pragma unroll
            for (int g = 0; g < 4; ++g) {
                const bf16x8 va = *(const bf16x8*)&Vt[cur][(g * 16 + col) * KSd + kc * 32 + quad * 8];
                #pragma unroll
                for (int u = 0; u < 2; ++u)
                    o[g][u] = __builtin_amdgcn_mfma_f32_16x16x32_bf16(va, pb[u], o[g][u], 0, 0, 0);
            }
        }
        __builtin_amdgcn_s_setprio(0);
        // tile-boundary barrier: LDS-only wait; mask/KV prefetch stays in
        // flight (they complete via compiler-counted vmcnt at use sites).
        lds_barrier();
    }

    // ---- deferred l reduction (quads hold disjoint key subsets) ----
    #pragma unroll
    for (int u = 0; u < 2; ++u) {
        lsum[u] += __shfl_xor(lsum[u], 16, 64);
        lsum[u] += __shfl_xor(lsum[u], 32, 64);
    }

    // ---- epilogue: lane (quad,r,col) holds O[q=qw+u*16+col][d=g*16+quad*4+r]
    #pragma unroll
    for (int u = 0; u < 2; ++u) {
        const float inv = 1.f / lsum[u];
        float* op = out + ((size_t)b * S + qw + u * 16 + col) * DM + h * Dh + quad * 4;
        #pragma unroll
        for (int g = 0; g < 4; ++g) {
            float4 ov;
            ov.x = o[g][u][0] * inv; ov.y = o[g][u][1] * inv;
            ov.z = o[g][u][2] * inv; ov.w = o[g][u][3] * inv;
            *(float4*)(op + g * 16) = ov;
        }
    }
}

// ---------------------------------------------------------------------------
extern "C" void kernel_launch(void* const* d_in, const int* in_sizes, int n_in,
                              void* d_out, int out_size, void* d_ws, size_t ws_size,
                              hipStream_t stream) {
    const float* hs   = (const float*)d_in[0];  // (B,S,DM)
    const float* mask = (const float*)d_in[1];  // (B,1,S,S)
    const int*   pos  = (const int*)  d_in[2];  // (B,S)
    const float* Wq   = (const float*)d_in[3];
    const float* Wk   = (const float*)d_in[4];
    const float* Wv   = (const float*)d_in[5];
    float* out = (float*)d_out;

    // workspace (ushort units): Xb 4,194,304 | Wb 3,145,728 |
    //   Qb,Kb [B,H,S,Dh], Vb [B,H,Dh,S] each 4,194,304 | Tab 1 MB (float2)
    unsigned short* Xb = (unsigned short*)d_ws;
    unsigned short* Wb = Xb + 4194304;
    unsigned short* Qb = Wb + 3145728;
    unsigned short* Kb = Qb + 4194304;
    unsigned short* Vb = Kb + 4194304;
    float*          Tab = (float*)(Vb + 4194304);   // 262144 floats

    cast_rope_kernel<<<7680, 256, 0, stream>>>(hs, Wq, Wk, Wv, pos, Xb, Wb, Tab);
    qkv_gemm<<<dim3(32, 24), 256, 0, stream>>>(Xb, Wb, Tab, Qb, Kb, Vb);
    attn_kernel<<<dim3(S / 128, BH), 256, 0, stream>>>(Qb, Kb, Vb, mask, out);
}

// Round 12
// 220.255 us; speedup vs baseline: 1.4224x; 1.0280x over previous
//
#include <hip/hip_runtime.h>
#include <math.h>

// Problem constants (from reference)
#define B  2
#define S  2048
#define DM 1024
#define H  16
#define Dh 64
#define BH (B*H)

typedef short  bf16x8 __attribute__((ext_vector_type(8)));
typedef float  f32x4  __attribute__((ext_vector_type(4)));

__device__ __forceinline__ unsigned short f2bf(float f) {
    unsigned u = __float_as_uint(f);
    u = (u + 0x7fffu + ((u >> 16) & 1u)) >> 16;   // RNE, no NaN inputs here
    return (unsigned short)u;
}

// gfx950 packed f32->bf16 (RNE) — one VALU op for two converts+pack.
__device__ __forceinline__ unsigned cvt_pk_bf16(float lo, float hi) {
    unsigned r;
    asm("v_cvt_pk_bf16_f32 %0, %1, %2" : "=v"(r) : "v"(lo), "v"(hi));
    return r;
}

// Barrier that waits ONLY on LDS ops (lgkmcnt), leaving global-load register
// prefetch in flight across the barrier. Two-sided compiler fence REQUIRED
// (R6 failure: s_barrier is IntrNoMem; without the trailing fence, post-
// barrier LDS reads hoist between the waitcnt and the barrier).
__device__ __forceinline__ void lds_barrier() {
    asm volatile("s_waitcnt lgkmcnt(0)" ::: "memory");
    __builtin_amdgcn_s_barrier();
    asm volatile("" ::: "memory");
}

// ---------------------------------------------------------------------------
// Kernel 0a: cast hidden_states + Wq|Wk|Wv (fp32) to bf16 workspace buffers.
// ---------------------------------------------------------------------------
__global__ __launch_bounds__(256) void cast_kernel(const float* __restrict__ X,
                                                   const float* __restrict__ Wq,
                                                   const float* __restrict__ Wk,
                                                   const float* __restrict__ Wv,
                                                   unsigned short* __restrict__ Xb,
                                                   unsigned short* __restrict__ Wb) {
    const long c = (long)(blockIdx.x * 256 + threadIdx.x) * 4;
    const float* src;
    unsigned short* dst;
    if (c < 4194304L) {
        src = X + c;  dst = Xb + c;
    } else {
        const long c2 = c - 4194304L;
        const int  wi = (int)(c2 >> 20);
        const long r  = c2 & 1048575L;
        src = (wi == 0 ? Wq : (wi == 1 ? Wk : Wv)) + r;
        dst = Wb + c2;
    }
    const float4 v = *(const float4*)src;
    ushort4 o;
    o.x = f2bf(v.x); o.y = f2bf(v.y); o.z = f2bf(v.z); o.w = f2bf(v.w);
    *(ushort4*)dst = o;
}

// ---------------------------------------------------------------------------
// Kernel 0b: RoPE cos/sin table: Tab[(b*S+s)*32 + i] = (cos, sin) of
//   pos[b,s] * 10000^(-i/32).  1 MB, L2-resident.
// ---------------------------------------------------------------------------
__global__ __launch_bounds__(256) void rope_tab_kernel(const int* __restrict__ pos,
                                                       float* __restrict__ Tab) {
    const int idx = blockIdx.x * 256 + threadIdx.x;   // < B*S*32 = 131072
    const int i  = idx & 31;
    const int bs = idx >> 5;
    const float p   = (float)pos[bs];
    const float inv = exp2f(-(float)i * 0.41524101186092029f);  // log2(1e4)/32
    float sn, cs;
    sincosf(p * inv, &sn, &cs);
    ((float2*)Tab)[idx] = make_float2(cs, sn);
}

// async global->LDS, 16B per lane
__device__ __forceinline__ void gload_lds16(const unsigned short* g, unsigned short* l) {
    __builtin_amdgcn_global_load_lds(
        (const __attribute__((address_space(1))) unsigned int*)g,
        (__attribute__((address_space(3))) unsigned int*)l,
        16, 0, 0);
}

// ---------------------------------------------------------------------------
// Kernel 1: fused QKV GEMM (R0 verified config: BK=32, 16 MFMA/barrier —
//   BK=64 (R3), XCD swizzle (R9), 256² 2-phase (R10) all regressed; ~300 TF
//   is ON m102's shape curve for 2048-class shapes). global_load_lds staging
//   with XOR chunk swizzle. Epilogue: RoPE via table + LDS round-trip (Es,
//   2 halves) so ALL global stores are coalesced 16B. V written transposed
//   [B,H,Dh,S].
// ---------------------------------------------------------------------------
__global__ __launch_bounds__(256) void qkv_gemm(const unsigned short* __restrict__ Xb,
                                                const unsigned short* __restrict__ Wb,
                                                const float* __restrict__ Tab,
                                                unsigned short* __restrict__ Qb,
                                                unsigned short* __restrict__ Kb,
                                                unsigned short* __restrict__ Vb) {
    __shared__ __align__(16) unsigned short As[128 * 32];
    __shared__ __align__(16) unsigned short Bs[128 * 32];
    __shared__ __align__(16) unsigned short Es[64 * 136];   // epilogue staging

    const int tid  = threadIdx.x;
    const int w    = tid >> 6;
    const int lane = tid & 63;
    const int col  = lane & 15;
    const int quad = lane >> 4;
    const int m0 = blockIdx.x * 128;
    const int n0 = blockIdx.y * 128;
    const int mw = (w & 1) * 64;
    const int nw = (w >> 1) * 64;

    // staging: lane i loads row i>>2, global chunk (i&3)^(row&3)  (XOR swizzle)
    const int srow = lane >> 2;
    const int sk8  = (((lane & 3) ^ (srow & 3))) * 8;

    f32x4 acc[4][4] = {};

    for (int k0 = 0; k0 < 1024; k0 += 32) {
        __syncthreads();
        #pragma unroll
        for (int it = 0; it < 2; ++it) {
            const int rbase = w * 16 + it * 64;
            gload_lds16(Xb + (size_t)(m0 + rbase + srow) * 1024 + k0 + sk8,
                        &As[rbase * 32]);
            gload_lds16(Wb + (size_t)(n0 + rbase + srow) * 1024 + k0 + sk8,
                        &Bs[rbase * 32]);
        }
        __syncthreads();

        // global k-chunk quad lives at LDS slot quad^(row&3); row&3 == col&3
        const int fs = (quad ^ (col & 3)) * 8;
        bf16x8 a[4], bb[4];
        #pragma unroll
        for (int i = 0; i < 4; ++i)
            a[i] = *(const bf16x8*)&As[(mw + i * 16 + col) * 32 + fs];
        #pragma unroll
        for (int j = 0; j < 4; ++j)
            bb[j] = *(const bf16x8*)&Bs[(nw + j * 16 + col) * 32 + fs];
        #pragma unroll
        for (int i = 0; i < 4; ++i)
            #pragma unroll
            for (int j = 0; j < 4; ++j)
                acc[i][j] = __builtin_amdgcn_mfma_f32_16x16x32_bf16(a[i], bb[j], acc[i][j], 0, 0, 0);
    }

    // ---- epilogue ----
    const int wsel = n0 >> 10;                 // 0=Q, 1=K, 2=V
    const int hh0  = (n0 & 1023) >> 6;         // base head of this n-tile
    const int bb2  = m0 >> 11;                 // batch (block never straddles)
    const int ssb  = m0 & 2047;                // seq base

    if (wsel == 2) {
        // V -> [B,H,Dh,S]; Es[dl][ssl] per dcol-half, b64 packed writes
        #pragma unroll
        for (int half = 0; half < 2; ++half) {
            __syncthreads();
            if ((w >> 1) == half) {            // waves whose nw == half*64
                #pragma unroll
                for (int i = 0; i < 4; ++i) {
                    const int sl = mw + i * 16 + quad * 4;
                    #pragma unroll
                    for (int j = 0; j < 4; ++j) {
                        const int dl = j * 16 + col;     // 0..63 within half
                        ushort4 ov;
                        ov.x = f2bf(acc[i][j][0]); ov.y = f2bf(acc[i][j][1]);
                        ov.z = f2bf(acc[i][j][2]); ov.w = f2bf(acc[i][j][3]);
                        *(ushort4*)&Es[dl * 136 + sl] = ov;
                    }
                }
            }
            __syncthreads();
            #pragma unroll
            for (int k = 0; k < 4; ++k) {
                const int c  = tid + k * 256;
                const int dl = c >> 4;               // 0..63 within half
                const int s8 = (c & 15) * 8;
                const int d  = half * 64 + dl;
                const bf16x8 v = *(const bf16x8*)&Es[dl * 136 + s8];
                *(bf16x8*)(Vb + ((size_t)(bb2 * H + hh0 + (d >> 6)) * Dh + (d & 63)) * S
                           + ssb + s8) = v;
            }
        }
    } else {
        // Q/K with fused RoPE from table; Es[row][d] per m-half
        unsigned short* dp = (wsel == 0) ? Qb : Kb;
        const float qscale = (wsel == 0) ? 0.125f : 1.0f;   // D^-0.5 for Q
        #pragma unroll
        for (int half = 0; half < 2; ++half) {
            __syncthreads();
            if ((w & 1) == half) {             // waves whose mw == half*64
                #pragma unroll
                for (int i = 0; i < 4; ++i) {
                    #pragma unroll
                    for (int r = 0; r < 4; ++r) {
                        const int rl = i * 16 + quad * 4 + r;   // 0..63 local
                        const int ss = ssb + half * 64 + rl;
                        const float2 t0 = ((const float2*)Tab)[(size_t)(bb2 * S + ss) * 32 + col];
                        const float2 t1 = ((const float2*)Tab)[(size_t)(bb2 * S + ss) * 32 + col + 16];
                        const float a0 = acc[i][0][r] * qscale, a1 = acc[i][1][r] * qscale;
                        const float a2 = acc[i][2][r] * qscale, a3 = acc[i][3][r] * qscale;
                        unsigned short* e = &Es[rl * 136 + nw];
                        e[col]      = f2bf(a0 * t0.x - a2 * t0.y);
                        e[col + 16] = f2bf(a1 * t1.x - a3 * t1.y);
                        e[col + 32] = f2bf(a2 * t0.x + a0 * t0.y);
                        e[col + 48] = f2bf(a3 * t1.x + a1 * t1.y);
                    }
                }
            }
            __syncthreads();
            #pragma unroll
            for (int k = 0; k < 4; ++k) {
                const int c  = tid + k * 256;
                const int rl = c >> 4;               // 0..63 local row
                const int d8 = (c & 15) * 8;
                const bf16x8 v = *(const bf16x8*)&Es[rl * 136 + d8];
                *(bf16x8*)(dp + ((size_t)(bb2 * H + hh0 + (d8 >> 6)) * S
                                 + ssb + half * 64 + rl) * Dh + (d8 & 63)) = v;
            }
        }
    }
}

// ---------------------------------------------------------------------------
// Kernel 2: flash attention — R7 verified version (best attn: 87.0 µs).
//   Counted-wait barriers (two-sided-fence lds_barrier), mask(kt+1)/KV(kt+2)
//   register prefetch, LDS K/V staging for coalescing (R8 proved de-staging
//   loses 2x to uncoalesced fragment loads). NO setprio (R11: −6.5 µs — the
//   4-wave lockstep + 2-block co-schedule regime is hurt by it).
//   grid = (S/128, B*H) = 512 blocks, 256 thr.
// ---------------------------------------------------------------------------
#define KSd 72
#define LOG2E  1.4426950408889634f
#define NEG8L (-11.541560327111707f)      // -8 * log2(e); exp(s-8) == exp2(fma)
#define NT (S / 64)

__global__ __launch_bounds__(256) void attn_kernel(const unsigned short* __restrict__ Q,
                                                   const unsigned short* __restrict__ K,
                                                   const unsigned short* __restrict__ V,
                                                   const float* __restrict__ mask,
                                                   float* __restrict__ out) {
    __shared__ __align__(16) unsigned short Ks[2][64 * KSd];   // [key][d]
    __shared__ __align__(16) unsigned short Vt[2][64 * KSd];   // [d][key]
    __shared__ __align__(16) unsigned short Ps[4 * 32 * KSd];

    const int tid  = threadIdx.x;
    const int w    = tid >> 6;
    const int lane = tid & 63;
    const int col  = lane & 15;
    const int quad = lane >> 4;
    const int bh   = blockIdx.y;
    const int b    = bh >> 4, h = bh & 15;
    const int q0   = blockIdx.x * 128;
    const int qw   = q0 + w * 32;             // wave's q base (32 rows)

    const int srow = tid >> 3;            // 0..31
    const int sc8  = (tid & 7) * 8;

    // Q fragments: qa[u][kc] — lane holds Q[q=qw+u*16+col][kc*32+quad*8 ..+7]
    bf16x8 qa[2][2];
    #pragma unroll
    for (int u = 0; u < 2; ++u) {
        const unsigned short* qrow = Q + ((size_t)bh * S + qw + u * 16 + col) * Dh;
        qa[u][0] = *(const bf16x8*)(qrow + quad * 8);
        qa[u][1] = *(const bf16x8*)(qrow + 32 + quad * 8);
    }

    f32x4 o[4][2] = {};                        // O^T frags: [d-frag g][q-frag u]
    float lsum[2] = {0.f, 0.f};
    const float* mbase = mask + (size_t)b * S * S;
    unsigned short* pw = Ps + w * 32 * KSd;
    const unsigned short* Kbase = K + (size_t)bh * S * Dh;
    const unsigned short* Vbase = V + (size_t)bh * Dh * S;   // transposed

    // ---- prologue: tile0 K/V + mask(tile0) into regs; stage tile0 to LDS
    //      buffer 0; then pre-issue tile1 K/V loads (drained at kt=0). ----
    bf16x8 kp[2], vp[2];
    float4 mv[4][2];
    #pragma unroll
    for (int cc = 0; cc < 2; ++cc) {
        kp[cc] = *(const bf16x8*)(Kbase + (size_t)(srow + cc * 32) * Dh + sc8);
        vp[cc] = *(const bf16x8*)(Vbase + (size_t)(srow + cc * 32) * S + sc8);
    }
    #pragma unroll
    for (int u = 0; u < 2; ++u)
        #pragma unroll
        for (int f = 0; f < 4; ++f)
            mv[f][u] = *(const float4*)(mbase + (size_t)(qw + u * 16 + col) * S
                                        + f * 16 + quad * 4);
    #pragma unroll
    for (int cc = 0; cc < 2; ++cc) {
        const int row = srow + cc * 32;
        *(bf16x8*)&Ks[0][row * KSd + sc8] = kp[cc];
        *(bf16x8*)&Vt[0][row * KSd + sc8] = vp[cc];
    }
    #pragma unroll
    for (int cc = 0; cc < 2; ++cc) {        // issue tile1 (stays in flight)
        kp[cc] = *(const bf16x8*)(Kbase + (size_t)(64 + srow + cc * 32) * Dh + sc8);
        vp[cc] = *(const bf16x8*)(Vbase + (size_t)(srow + cc * 32) * S + 64 + sc8);
    }
    lds_barrier();

    for (int kt = 0; kt < NT; ++kt) {
        const int cur = kt & 1;

        // ---- S^T = K · Q^T : C[m=key][n=q] ----
        f32x4 sc[4][2] = {};
        #pragma unroll
        for (int f = 0; f < 4; ++f) {
            const bf16x8 ka0 = *(const bf16x8*)&Ks[cur][(f * 16 + col) * KSd + quad * 8];
            const bf16x8 ka1 = *(const bf16x8*)&Ks[cur][(f * 16 + col) * KSd + 32 + quad * 8];
            #pragma unroll
            for (int u = 0; u < 2; ++u) {
                sc[f][u] = __builtin_amdgcn_mfma_f32_16x16x32_bf16(ka0, qa[u][0], sc[f][u], 0, 0, 0);
                sc[f][u] = __builtin_amdgcn_mfma_f32_16x16x32_bf16(ka1, qa[u][1], sc[f][u], 0, 0, 0);
            }
        }

        // ---- static-shift softmax numerator + packed P̃ store (consumes mv) ----
        #pragma unroll
        for (int u = 0; u < 2; ++u) {
            #pragma unroll
            for (int f = 0; f < 4; ++f) {
                sc[f][u][0] += mv[f][u].x; sc[f][u][1] += mv[f][u].y;
                sc[f][u][2] += mv[f][u].z; sc[f][u][3] += mv[f][u].w;
            }
            #pragma unroll
            for (int f = 0; f < 4; ++f)
                #pragma unroll
                for (int r = 0; r < 4; ++r) {
                    const float pv = __builtin_amdgcn_exp2f(
                        __builtin_fmaf(sc[f][u][r], LOG2E, NEG8L));
                    sc[f][u][r] = pv;
                    lsum[u] += pv;
                }
            unsigned short* pq = pw + (u * 16 + col) * KSd;
            #pragma unroll
            for (int f = 0; f < 4; ++f) {
                *(uint2*)&pq[f * 16 + quad * 4] =
                    make_uint2(cvt_pk_bf16(sc[f][u][0], sc[f][u][1]),
                               cvt_pk_bf16(sc[f][u][2], sc[f][u][3]));
            }
        }

        // ---- mv dead: issue mask loads for tile kt+1 directly into mv ----
        if (kt + 1 < NT) {
            #pragma unroll
            for (int u = 0; u < 2; ++u)
                #pragma unroll
                for (int f = 0; f < 4; ++f)
                    mv[f][u] = *(const float4*)(mbase + (size_t)(qw + u * 16 + col) * S
                                                + (kt + 1) * 64 + f * 16 + quad * 4);
        }

        // ---- drain K/V(kt+1) into LDS[nxt]; then issue K/V(kt+2) loads ----
        if (kt + 1 < NT) {
            const int nxt = cur ^ 1;
            #pragma unroll
            for (int cc = 0; cc < 2; ++cc) {
                const int row = srow + cc * 32;
                *(bf16x8*)&Ks[nxt][row * KSd + sc8] = kp[cc];
                *(bf16x8*)&Vt[nxt][row * KSd + sc8] = vp[cc];
            }
            if (kt + 2 < NT) {
                #pragma unroll
                for (int cc = 0; cc < 2; ++cc) {
                    kp[cc] = *(const bf16x8*)(Kbase + (size_t)((kt + 2) * 64 + srow + cc * 32) * Dh + sc8);
                    vp[cc] = *(const bf16x8*)(Vbase + (size_t)(srow + cc * 32) * S + (kt + 2) * 64 + sc8);
                }
            }
        }

        // wave-private Ps write->read ordering (same-wave): LDS wait + fence.
        asm volatile("s_waitcnt lgkmcnt(0)" ::: "memory");
        __builtin_amdgcn_sched_barrier(0);

        // ---- O^T += V^T · P̃ ----
        #pragma unroll
        for (int kc = 0; kc < 2; ++kc) {
            bf16x8 pb[2];
            #pragma unroll
            for (int u = 0; u < 2; ++u)
                pb[u] = *(const bf16x8*)&pw[(u * 16 + col) * KSd + kc * 32 + quad * 8];
            #pragma unroll
            for (int g = 0; g < 4; ++g) {
                const bf16x8 va = *(const bf16x8*)&Vt[cur][(g * 16 + col) * KSd + kc * 32 + quad * 8];
                #pragma unroll
                for (int u = 0; u < 2; ++u)
                    o[g][u] = __builtin_amdgcn_mfma_f32_16x16x32_bf16(va, pb[u], o[g][u], 0, 0, 0);
            }
        }
        // tile-boundary barrier: LDS-only wait; mask/KV prefetch stays in
        // flight (they complete via compiler-counted vmcnt at use sites).
        lds_barrier();
    }

    // ---- deferred l reduction (quads hold disjoint key subsets) ----
    #pragma unroll
    for (int u = 0; u < 2; ++u) {
        lsum[u] += __shfl_xor(lsum[u], 16, 64);
        lsum[u] += __shfl_xor(lsum[u], 32, 64);
    }

    // ---- epilogue: lane (quad,r,col) holds O[q=qw+u*16+col][d=g*16+quad*4+r]
    #pragma unroll
    for (int u = 0; u < 2; ++u) {
        const float inv = 1.f / lsum[u];
        float* op = out + ((size_t)b * S + qw + u * 16 + col) * DM + h * Dh + quad * 4;
        #pragma unroll
        for (int g = 0; g < 4; ++g) {
            float4 ov;
            ov.x = o[g][u][0] * inv; ov.y = o[g][u][1] * inv;
            ov.z = o[g][u][2] * inv; ov.w = o[g][u][3] * inv;
            *(float4*)(op + g * 16) = ov;
        }
    }
}

// ---------------------------------------------------------------------------
extern "C" void kernel_launch(void* const* d_in, const int* in_sizes, int n_in,
                              void* d_out, int out_size, void* d_ws, size_t ws_size,
                              hipStream_t stream) {
    const float* hs   = (const float*)d_in[0];  // (B,S,DM)
    const float* mask = (const float*)d_in[1];  // (B,1,S,S)
    const int*   pos  = (const int*)  d_in[2];  // (B,S)
    const float* Wq   = (const float*)d_in[3];
    const float* Wk   = (const float*)d_in[4];
    const float* Wv   = (const float*)d_in[5];
    float* out = (float*)d_out;

    // workspace (ushort units): Xb 4,194,304 | Wb 3,145,728 |
    //   Qb,Kb [B,H,S,Dh], Vb [B,H,Dh,S] each 4,194,304 | Tab 1 MB (float2)
    unsigned short* Xb = (unsigned short*)d_ws;
    unsigned short* Wb = Xb + 4194304;
    unsigned short* Qb = Wb + 3145728;
    unsigned short* Kb = Qb + 4194304;
    unsigned short* Vb = Kb + 4194304;
    float*          Tab = (float*)(Vb + 4194304);   // 262144 floats

    cast_kernel<<<7168, 256, 0, stream>>>(hs, Wq, Wk, Wv, Xb, Wb);
    rope_tab_kernel<<<512, 256, 0, stream>>>(pos, Tab);
    qkv_gemm<<<dim3(32, 24), 256, 0, stream>>>(Xb, Wb, Tab, Qb, Kb, Vb);
    attn_kernel<<<dim3(S / 128, BH), 256, 0, stream>>>(Qb, Kb, Vb, mask, out);
}